// Round 1
// baseline (3547.238 us; speedup 1.0000x reference)
//
#include <hip/hip_runtime.h>
#include <hip/hip_bf16.h>
#include <cstdint>

// Problem constants
#define NB     2
#define LSEQ   2048
#define DMODEL 2048
#define DINNER 4096
#define NHEADS 64
#define HD     64
#define DSTATE 64
#define NCHUNK 8
#define CHK    256
#define CONVD  4224
#define DPROJ  8384
#define NTOK   4096

// workspace offsets (floats)
#define ZX_OFF   0ul
#define DTB_OFF  34340864ul   // [b][h][l] dt (softplus'd)
#define ACU_OFF  34603008ul   // [b][h][l] within-chunk cumsum of dt*A
#define CBT_OFF  34865152ul   // [b][c][s][l]  (C·B^T)^T
#define CCT_OFF  35913728ul   // [b][c][n][l]  C transposed
#define ST_OFF   36175872ul   // [b][c][h][p][n] states -> prev_states (in place)
#define YB_OFF   40370176ul   // [b][h][l][p] ssd output -> normed (in place)
#define HALO_OFF 57147392ul   // [b][lc][3][ch] conv halo

// ---------------- GEMM (NT): C[M][N] = A[M][K] * Bw[N][K]^T ------------------
// AMODE 0: A row-major stride K.  AMODE 1: A in yb layout [b][h][l][p].
template <int AMODE>
__global__ __launch_bounds__(256) void gemm_nt(const float* __restrict__ A,
                                               const float* __restrict__ Bw,
                                               float* __restrict__ C, int M,
                                               int N, int K, int ldc) {
  __shared__ __align__(16) float As[16][128];
  __shared__ __align__(16) float Bs[16][64];
  const int tid = threadIdx.x;
  const int m0 = blockIdx.y * 128, n0 = blockIdx.x * 64;
  const int tm = tid & 15, tn = tid >> 4;
  const int am = tid >> 1;        // 0..127 staging row
  const int akq = (tid & 1) * 8;  // 0 or 8
  const int bn = tid >> 2;        // 0..63
  const int bk = (tid & 3) * 4;   // 0,4,8,12
  float acc[8][4];
#pragma unroll
  for (int i = 0; i < 8; ++i)
#pragma unroll
    for (int j = 0; j < 4; ++j) acc[i][j] = 0.f;

  for (int k0 = 0; k0 < K; k0 += 16) {
    float4 a0, a1, b0;
    if (AMODE == 0) {
      const float* ap = A + (size_t)(m0 + am) * K + k0 + akq;
      a0 = *(const float4*)ap;
      a1 = *(const float4*)(ap + 4);
    } else {
      const int m = m0 + am, k = k0 + akq;
      const float* ap =
          A + ((size_t)((m >> 11) * 64 + (k >> 6)) * 2048 + (m & 2047)) * 64 +
          (k & 63);
      a0 = *(const float4*)ap;
      a1 = *(const float4*)(ap + 4);
    }
    b0 = *(const float4*)(Bw + (size_t)(n0 + bn) * K + k0 + bk);
    __syncthreads();
    As[akq + 0][am] = a0.x; As[akq + 1][am] = a0.y;
    As[akq + 2][am] = a0.z; As[akq + 3][am] = a0.w;
    As[akq + 4][am] = a1.x; As[akq + 5][am] = a1.y;
    As[akq + 6][am] = a1.z; As[akq + 7][am] = a1.w;
    Bs[bk + 0][bn] = b0.x; Bs[bk + 1][bn] = b0.y;
    Bs[bk + 2][bn] = b0.z; Bs[bk + 3][bn] = b0.w;
    __syncthreads();
#pragma unroll
    for (int kk = 0; kk < 16; ++kk) {
      float4 x0 = *(const float4*)&As[kk][tm * 8];
      float4 x1 = *(const float4*)&As[kk][tm * 8 + 4];
      float4 y0 = *(const float4*)&Bs[kk][tn * 4];
      float av[8] = {x0.x, x0.y, x0.z, x0.w, x1.x, x1.y, x1.z, x1.w};
      float bv[4] = {y0.x, y0.y, y0.z, y0.w};
#pragma unroll
      for (int i = 0; i < 8; ++i)
#pragma unroll
        for (int j = 0; j < 4; ++j) acc[i][j] += av[i] * bv[j];
    }
  }
#pragma unroll
  for (int i = 0; i < 8; ++i) {
    float4 o = make_float4(acc[i][0], acc[i][1], acc[i][2], acc[i][3]);
    *(float4*)&C[(size_t)(m0 + tm * 8 + i) * ldc + n0 + tn * 4] = o;
  }
}

// ---------------- conv halo save (before in-place conv) ----------------------
__global__ __launch_bounds__(256) void halo_kernel(const float* __restrict__ zx,
                                                   float* __restrict__ halo) {
  int idx = blockIdx.x * 256 + threadIdx.x;  // < 2*16*3*4224
  int ch = idx % 4224;
  int r = idx / 4224;
  int j = r % 3;
  int r2 = r / 3;
  int lc = r2 & 15, b = r2 >> 4;
  int l = lc * 128 - 3 + j;
  halo[idx] = (l < 0) ? 0.f : zx[(size_t)(b * 2048 + l) * DPROJ + 4096 + ch];
}

// ---------------- causal conv1d(4) + silu, in place on xBC slice -------------
__global__ __launch_bounds__(256) void conv_kernel(float* __restrict__ zx,
                                                   const float* __restrict__ halo,
                                                   const float* __restrict__ cw,
                                                   const float* __restrict__ cb) {
  int idx = blockIdx.x * 256 + threadIdx.x;  // < 2*16*4224
  int ch = idx % 4224;
  int r = idx / 4224;  // b*16+lc
  int lc = r & 15, b = r >> 4;
  float w0 = cw[ch * 4 + 0], w1 = cw[ch * 4 + 1], w2 = cw[ch * 4 + 2],
        w3 = cw[ch * 4 + 3];
  float bias = cb[ch];
  const float* hp = halo + (size_t)r * 3 * 4224 + ch;
  float x3 = hp[0], x2 = hp[4224], x1 = hp[2 * 4224];
  size_t base = (size_t)(b * 2048 + lc * 128) * DPROJ + 4096 + ch;
  for (int i = 0; i < 128; ++i) {
    float x0 = zx[base];
    float v = bias + w0 * x3 + w1 * x2 + w2 * x1 + w3 * x0;
    v = v / (1.f + __expf(-v));  // silu
    zx[base] = v;
    x3 = x2; x2 = x1; x1 = x0;
    base += DPROJ;
  }
}

// ---------------- dt softplus + per-chunk cumsum of dt*A ---------------------
__global__ __launch_bounds__(256) void dtacum_kernel(
    const float* __restrict__ zx, const float* __restrict__ dt_bias,
    const float* __restrict__ A_log, float* __restrict__ dtb,
    float* __restrict__ acu) {
  int bid = blockIdx.x;  // (b*64+h)*8 + c
  int c = bid & 7, h = (bid >> 3) & 63, b = bid >> 9;
  int s = threadIdx.x;
  int tok = b * 2048 + c * 256 + s;
  float raw = zx[(size_t)tok * DPROJ + 8320 + h] + dt_bias[h];
  float dtv = (raw > 20.f) ? raw : log1pf(expf(raw));
  float A = -expf(A_log[h]);
  __shared__ float sc[256];
  sc[s] = dtv * A;
  __syncthreads();
  for (int off = 1; off < 256; off <<= 1) {
    float v = (s >= off) ? sc[s - off] : 0.f;
    __syncthreads();
    sc[s] += v;
    __syncthreads();
  }
  int o = (b * 64 + h) * 2048 + c * 256 + s;
  dtb[o] = dtv;
  acu[o] = sc[s];
}

// ---------------- CB^T per (b,c): cbt[s][l] = sum_n C[l,n]*B[s,n] ------------
__global__ __launch_bounds__(256) void cbt_kernel(const float* __restrict__ zx,
                                                  float* __restrict__ cbt) {
  __shared__ float cl[256][33];
  __shared__ float blds[16][32];
  int bid = blockIdx.x;  // (b*8+c)*16 + sb
  int sb = bid & 15, c = (bid >> 4) & 7, b = bid >> 7;
  int t = threadIdx.x;
  int tok0 = b * 2048 + c * 256;
  float acc[16];
#pragma unroll
  for (int i = 0; i < 16; ++i) acc[i] = 0.f;
  for (int nh = 0; nh < 2; ++nh) {
    __syncthreads();
    for (int it = 0; it < 32; ++it) {
      int e = it * 256 + t;
      int row = e >> 5, n = e & 31;
      cl[row][n] = zx[(size_t)(tok0 + row) * DPROJ + 8256 + nh * 32 + n];
    }
    for (int it = 0; it < 2; ++it) {
      int e = it * 256 + t;
      int row = e >> 5, n = e & 31;
      blds[row][n] =
          zx[(size_t)(tok0 + sb * 16 + row) * DPROJ + 8192 + nh * 32 + n];
    }
    __syncthreads();
    for (int n = 0; n < 32; ++n) {
      float cv = cl[t][n];
#pragma unroll
      for (int s2 = 0; s2 < 16; ++s2) acc[s2] += cv * blds[s2][n];
    }
  }
#pragma unroll
  for (int s2 = 0; s2 < 16; ++s2)
    cbt[((size_t)(b * 8 + c) * 256 + sb * 16 + s2) * 256 + t] = acc[s2];
}

// ---------------- C transpose: cct[b][c][n][l] -------------------------------
__global__ __launch_bounds__(256) void ctrans_kernel(const float* __restrict__ zx,
                                                     float* __restrict__ cct) {
  int idx = blockIdx.x * 256 + threadIdx.x;  // ((b*8+c)*64+n)*256 + l
  int l = idx & 255, n = (idx >> 8) & 63, bc = idx >> 14;
  int b = bc >> 3, c = bc & 7;
  cct[idx] = zx[(size_t)(b * 2048 + c * 256 + l) * DPROJ + 8256 + n];
}

// ---------------- chunk states: st[p][n] = sum_s B[s,n] w[s] x[s,p] ----------
__global__ __launch_bounds__(256) void states_kernel(
    const float* __restrict__ zx, const float* __restrict__ dtb,
    const float* __restrict__ acu, float* __restrict__ st) {
  __shared__ __align__(16) float xl[64 * 64];
  __shared__ __align__(16) float bl[64 * 64];
  __shared__ float wl[256];
  int bid = blockIdx.x;  // (b*8+c)*64 + h
  int h = bid & 63, c = (bid >> 6) & 7, b = bid >> 9;
  int t = threadIdx.x;
  int tok0 = b * 2048 + c * 256;
  int bh = (b * 64 + h) * 2048 + c * 256;
  {
    float aend = acu[bh + 255];
    wl[t] = __expf(aend - acu[bh + t]) * dtb[bh + t];
  }
  int n = t & 63, p0 = (t >> 6) * 16;
  float acc[16];
#pragma unroll
  for (int i = 0; i < 16; ++i) acc[i] = 0.f;
  for (int sch = 0; sch < 4; ++sch) {
    __syncthreads();
    for (int it = 0; it < 4; ++it) {
      int e = it * 1024 + t * 4;
      int s = e >> 6, p = e & 63;
      *(float4*)&xl[e] = *(const float4*)&zx[(size_t)(tok0 + sch * 64 + s) * DPROJ +
                                             4096 + h * 64 + p];
      *(float4*)&bl[e] =
          *(const float4*)&zx[(size_t)(tok0 + sch * 64 + s) * DPROJ + 8192 + p];
    }
    __syncthreads();
    for (int s = 0; s < 64; ++s) {
      float bw = bl[s * 64 + n] * wl[sch * 64 + s];
#pragma unroll
      for (int i = 0; i < 16; ++i) acc[i] += bw * xl[s * 64 + p0 + i];
    }
  }
  float* out = st + ((size_t)(b * 8 + c) * 64 + h) * 4096;
#pragma unroll
  for (int i = 0; i < 16; ++i) out[(p0 + i) * 64 + n] = acc[i];
}

// ---------------- inter-chunk scan (in place states -> prev_states) ---------
__global__ __launch_bounds__(256) void chunkscan_kernel(
    const float* __restrict__ acu, float* __restrict__ st) {
  int bid = blockIdx.x;  // (b*64+h)*16 + pc
  int pc = bid & 15, h = (bid >> 4) & 63, b = bid >> 10;
  int pn = pc * 256 + threadIdx.x;
  int abase = (b * 64 + h) * 2048;
  float run = 0.f;
  for (int c = 0; c < 8; ++c) {
    size_t idx = ((size_t)(b * 8 + c) * 64 + h) * 4096 + pn;
    float s = st[idx];
    st[idx] = run;
    float ach = acu[abase + c * 256 + 255];
    run = run * __expf(ach) + s;
  }
}

// ---------------- Y = (CB∘L)·(x·dt) + diag(e^Acum)·C·prev^T + D·x ------------
__global__ __launch_bounds__(256) void ydiag_kernel(
    const float* __restrict__ zx, const float* __restrict__ dtb,
    const float* __restrict__ acu, const float* __restrict__ cbt,
    const float* __restrict__ cct, const float* __restrict__ st,
    const float* __restrict__ Dp, float* __restrict__ yb) {
  __shared__ __align__(16) float xa[320][36];
  __shared__ float acs[256];
  __shared__ float dts[256];
  int bid = blockIdx.x;  // (b*8+c)*64 + h
  int h = bid & 63, c = (bid >> 6) & 7, b = bid >> 9;
  int l = threadIdx.x;
  int tok0 = b * 2048 + c * 256;
  int bh = (b * 64 + h) * 2048 + c * 256;
  acs[l] = acu[bh + l];
  dts[l] = dtb[bh + l];
  __syncthreads();
  float Al = acs[l];
  float expAl = __expf(Al);
  float Dh = Dp[h];
  const float* cbt_b = cbt + (size_t)(b * 8 + c) * 256 * 256;
  const float* cct_b = cct + (size_t)(b * 8 + c) * 64 * 256;
  const float* st_b = st + ((size_t)(b * 8 + c) * 64 + h) * 4096;
  const int smax = l | 63;  // wave-uniform triangular cutoff

  for (int half = 0; half < 2; ++half) {
    const int p0 = half * 32;
    __syncthreads();
    for (int it = 0; it < 32; ++it) {
      int e = it * 256 + threadIdx.x;
      int s = e >> 5, pp = e & 31;
      xa[s][pp] = zx[(size_t)(tok0 + s) * DPROJ + 4096 + h * 64 + p0 + pp];
    }
    for (int it = 0; it < 8; ++it) {
      int e = it * 256 + threadIdx.x;
      int n = e & 63, pp = e >> 6;
      xa[256 + n][pp] = st_b[(p0 + pp) * 64 + n];
    }
    __syncthreads();
    float acc[32];
#pragma unroll
    for (int i = 0; i < 32; ++i) acc[i] = 0.f;
    for (int s = 0; s <= smax; ++s) {
      float w = 0.f;
      if (s <= l) w = cbt_b[s * 256 + l] * __expf(Al - acs[s]) * dts[s];
#pragma unroll
      for (int q = 0; q < 8; ++q) {
        float4 xv = *(const float4*)&xa[s][q * 4];
        acc[4 * q + 0] += w * xv.x;
        acc[4 * q + 1] += w * xv.y;
        acc[4 * q + 2] += w * xv.z;
        acc[4 * q + 3] += w * xv.w;
      }
    }
    for (int n = 0; n < 64; ++n) {
      float w = cct_b[n * 256 + l] * expAl;
#pragma unroll
      for (int q = 0; q < 8; ++q) {
        float4 xv = *(const float4*)&xa[256 + n][q * 4];
        acc[4 * q + 0] += w * xv.x;
        acc[4 * q + 1] += w * xv.y;
        acc[4 * q + 2] += w * xv.z;
        acc[4 * q + 3] += w * xv.w;
      }
    }
#pragma unroll
    for (int pp = 0; pp < 32; ++pp) acc[pp] += Dh * xa[l][pp];
    __syncthreads();
#pragma unroll
    for (int pp = 0; pp < 32; ++pp) xa[l][pp] = acc[pp];
    __syncthreads();
    for (int it = 0; it < 32; ++it) {
      int e = it * 256 + threadIdx.x;
      int s = e >> 5, pp = e & 31;
      yb[(size_t)(bh + s) * 64 + p0 + pp] = xa[s][pp];
    }
  }
}

// ---------------- gate with silu(z) + RMSNorm (in place on yb) ---------------
__global__ __launch_bounds__(256) void gatenorm_kernel(
    const float* __restrict__ zx, const float* __restrict__ nw,
    float* __restrict__ yb) {
  int tok = blockIdx.x;
  int b = tok >> 11, l = tok & 2047;
  int t = threadIdx.x;
  float g[16];
  float ss = 0.f;
#pragma unroll
  for (int i = 0; i < 16; ++i) {
    int d = i * 256 + t;
    int h = d >> 6, p = d & 63;
    float yv = yb[((size_t)(b * 64 + h) * 2048 + l) * 64 + p];
    float zv = zx[(size_t)tok * DPROJ + d];
    float gv = yv * (zv / (1.f + __expf(-zv)));
    g[i] = gv;
    ss += gv * gv;
  }
  for (int off = 32; off > 0; off >>= 1) ss += __shfl_down(ss, off);
  __shared__ float red[4];
  int wid = t >> 6, lane = t & 63;
  if (lane == 0) red[wid] = ss;
  __syncthreads();
  float tot = red[0] + red[1] + red[2] + red[3];
  float scale = rsqrtf(tot * (1.f / 4096.f) + 1e-5f);
#pragma unroll
  for (int i = 0; i < 16; ++i) {
    int d = i * 256 + t;
    int h = d >> 6, p = d & 63;
    yb[((size_t)(b * 64 + h) * 2048 + l) * 64 + p] = g[i] * scale * nw[d];
  }
}

extern "C" void kernel_launch(void* const* d_in, const int* in_sizes, int n_in,
                              void* d_out, int out_size, void* d_ws,
                              size_t ws_size, hipStream_t stream) {
  const float* u = (const float*)d_in[0];
  const float* W_in = (const float*)d_in[1];
  const float* conv_w = (const float*)d_in[2];
  const float* conv_b = (const float*)d_in[3];
  const float* dt_bias = (const float*)d_in[4];
  const float* A_log = (const float*)d_in[5];
  const float* Dp = (const float*)d_in[6];
  const float* norm_w = (const float*)d_in[7];
  const float* W_out = (const float*)d_in[8];
  float* out = (float*)d_out;
  float* ws = (float*)d_ws;

  float* zx = ws + ZX_OFF;
  float* dtb = ws + DTB_OFF;
  float* acu = ws + ACU_OFF;
  float* cbtb = ws + CBT_OFF;
  float* cct = ws + CCT_OFF;
  float* st = ws + ST_OFF;
  float* yb = ws + YB_OFF;
  float* halo = ws + HALO_OFF;

  // 1. in_proj: zx = u @ W_in^T   (4096 x 8384, K=2048)
  gemm_nt<0><<<dim3(131, 32), 256, 0, stream>>>(u, W_in, zx, 4096, 8384, 2048,
                                                8384);
  // 2. conv halo save, then in-place conv+silu on xBC slice
  halo_kernel<<<1584, 256, 0, stream>>>(zx, halo);
  conv_kernel<<<528, 256, 0, stream>>>(zx, halo, conv_w, conv_b);
  // 3. dt softplus + per-chunk cumsum(dt*A)
  dtacum_kernel<<<1024, 256, 0, stream>>>(zx, dt_bias, A_log, dtb, acu);
  // 4. shared C·B^T and C^T per (b,c)
  cbt_kernel<<<256, 256, 0, stream>>>(zx, cbtb);
  ctrans_kernel<<<1024, 256, 0, stream>>>(zx, cct);
  // 5. chunk states, then inter-chunk scan (in place -> prev_states)
  states_kernel<<<1024, 256, 0, stream>>>(zx, dtb, acu, st);
  chunkscan_kernel<<<2048, 256, 0, stream>>>(acu, st);
  // 6. Y (diag + off + D term) -> yb
  ydiag_kernel<<<1024, 256, 0, stream>>>(zx, dtb, acu, cbtb, cct, st, Dp, yb);
  // 7. gate + RMSNorm in place
  gatenorm_kernel<<<4096, 256, 0, stream>>>(zx, norm_w, yb);
  // 8. out_proj: out = yb @ W_out^T  (4096 x 2048, K=4096)
  gemm_nt<1><<<dim3(32, 32), 256, 0, stream>>>(yb, W_out, out, 4096, 2048, 4096,
                                               2048);
}

// Round 2
// 1133.691 us; speedup vs baseline: 3.1289x; 3.1289x over previous
//
#include <hip/hip_runtime.h>
#include <hip/hip_bf16.h>
#include <cstdint>

// Problem constants
#define DPROJ  8384

typedef __attribute__((ext_vector_type(8))) short short8;
typedef __attribute__((ext_vector_type(4))) float f32x4;

// workspace offsets (float units)
#define ZX_OFF     0ul
#define DTB_OFF    34340864ul   // [b][h][l] dt (softplus'd)
#define ACU_OFF    34603008ul   // [b][h][l] within-chunk cumsum of dt*A
#define CBT_OFF    34865152ul   // [b][c][s][l]  (C·B^T)^T
#define CCT_OFF    35913728ul   // [b][c][n][l]  C transposed
#define ST_OFF     36175872ul   // [b][c][h][p][n] states -> prev_states
#define YB_OFF     40370176ul   // [b][h][l][p] ssd output
#define HALO_OFF   57147392ul   // [b][lc][3][ch] conv halo
// aliases (disjoint lifetimes):
#define U16_OFF    40370176ul   // bf16 u  (dead before ydiag writes yb)
#define WIN16_OFF  48758784ul   // bf16 W_in (dead before halo written)
#define WOUT16_OFF 34340864ul   // bf16 W_out (written after ydiag frees dtb..st)
#define DTRAW_OFF  36175872ul   // fp32 dt raw [tok][64] (dead before states)

__device__ __forceinline__ short f2bf(float x) {
  union { float f; uint32_t u; } v{x};
  uint32_t r = (v.u + 0x7fff + ((v.u >> 16) & 1)) >> 16;
  return (short)r;
}

// ---------------- fp32 -> bf16 cast (8 elems/thread) -------------------------
__global__ __launch_bounds__(256) void cast_bf16_kernel(
    const float* __restrict__ in, short* __restrict__ out, int n8) {
  int i = blockIdx.x * 256 + threadIdx.x;
  if (i >= n8) return;
  const float4* p = (const float4*)(in + (size_t)i * 8);
  float4 a = p[0], b = p[1];
  short8 o;
  o[0] = f2bf(a.x); o[1] = f2bf(a.y); o[2] = f2bf(a.z); o[3] = f2bf(a.w);
  o[4] = f2bf(b.x); o[5] = f2bf(b.y); o[6] = f2bf(b.z); o[7] = f2bf(b.w);
  *(short8*)(out + (size_t)i * 8) = o;
}

// ---------------- bf16 MFMA GEMM (NT): C[M][N] = A[M][K] * B[N][K]^T ---------
// 128x128 tile, BK=32, 4 waves (2x2), 16x16x32 MFMA, global_load_lds staging.
__device__ __forceinline__ void gload16(const void* g, const void* l) {
  __builtin_amdgcn_global_load_lds(
      (const __attribute__((address_space(1))) void*)g,
      (__attribute__((address_space(3))) void*)l, 16, 0, 0);
}

__global__ __launch_bounds__(256) void gemm_bf16(
    const short* __restrict__ A, int lda, const short* __restrict__ B, int ldb,
    float* __restrict__ C, int ldc, int K, int Nvalid) {
  __shared__ __align__(16) short As[128 * 32];
  __shared__ __align__(16) short Bs[128 * 32];
  const int t = threadIdx.x;
  const int w = t >> 6, lane = t & 63;
  const int m0 = blockIdx.y * 128, n0 = blockIdx.x * 128;
  const int wr = (w >> 1) * 64, wc = (w & 1) * 64;
  const int arow = t >> 2, kk = (t & 3) * 8;  // staging: row, k-offset
  const int fr = lane & 15, fk = (lane >> 4) * 8;
  int br0 = n0 + arow;       if (br0 > Nvalid - 1) br0 = Nvalid - 1;
  int br1 = n0 + 64 + arow;  if (br1 > Nvalid - 1) br1 = Nvalid - 1;
  const short* pa0 = A + (size_t)(m0 + arow) * lda + kk;
  const short* pa1 = A + (size_t)(m0 + 64 + arow) * lda + kk;
  const short* pb0 = B + (size_t)br0 * ldb + kk;
  const short* pb1 = B + (size_t)br1 * ldb + kk;
  short* la = As + w * 512;
  short* lb = Bs + w * 512;
  f32x4 acc[4][4];
#pragma unroll
  for (int i = 0; i < 4; ++i)
#pragma unroll
    for (int j = 0; j < 4; ++j) acc[i][j] = (f32x4){0.f, 0.f, 0.f, 0.f};

  for (int k0 = 0; k0 < K; k0 += 32) {
    gload16(pa0 + k0, la);
    gload16(pa1 + k0, la + 2048);
    gload16(pb0 + k0, lb);
    gload16(pb1 + k0, lb + 2048);
    __syncthreads();
    short8 af[4], bg[4];
#pragma unroll
    for (int i = 0; i < 4; ++i) {
      af[i] = *(const short8*)&As[(wr + i * 16 + fr) * 32 + fk];
      bg[i] = *(const short8*)&Bs[(wc + i * 16 + fr) * 32 + fk];
    }
#pragma unroll
    for (int i = 0; i < 4; ++i)
#pragma unroll
      for (int j = 0; j < 4; ++j)
        acc[i][j] = __builtin_amdgcn_mfma_f32_16x16x32_bf16(af[i], bg[j],
                                                            acc[i][j], 0, 0, 0);
    __syncthreads();
  }
#pragma unroll
  for (int i = 0; i < 4; ++i) {
    const int row = m0 + wr + i * 16 + (lane >> 4) * 4;
#pragma unroll
    for (int j = 0; j < 4; ++j) {
      const int col = n0 + wc + j * 16 + fr;
      if (col < Nvalid) {
#pragma unroll
        for (int r = 0; r < 4; ++r)
          C[(size_t)(row + r) * ldc + col] = acc[i][j][r];
      }
    }
  }
}

// ---------------- small fp32 GEMM (NT) for dt columns ------------------------
// C[M][64] = A[M][K] * Bw[64][K]^T ; grid(1, M/128), BN=64 fixed.
__global__ __launch_bounds__(256) void gemm_f32_nt(const float* __restrict__ A,
                                                   const float* __restrict__ Bw,
                                                   float* __restrict__ C, int K,
                                                   int ldc) {
  __shared__ __align__(16) float As[16][128];
  __shared__ __align__(16) float Bs[16][64];
  const int tid = threadIdx.x;
  const int m0 = blockIdx.y * 128, n0 = blockIdx.x * 64;
  const int tm = tid & 15, tn = tid >> 4;
  const int am = tid >> 1;
  const int akq = (tid & 1) * 8;
  const int bn = tid >> 2;
  const int bk = (tid & 3) * 4;
  float acc[8][4];
#pragma unroll
  for (int i = 0; i < 8; ++i)
#pragma unroll
    for (int j = 0; j < 4; ++j) acc[i][j] = 0.f;

  for (int k0 = 0; k0 < K; k0 += 16) {
    const float* ap = A + (size_t)(m0 + am) * K + k0 + akq;
    float4 a0 = *(const float4*)ap;
    float4 a1 = *(const float4*)(ap + 4);
    float4 b0 = *(const float4*)(Bw + (size_t)(n0 + bn) * K + k0 + bk);
    __syncthreads();
    As[akq + 0][am] = a0.x; As[akq + 1][am] = a0.y;
    As[akq + 2][am] = a0.z; As[akq + 3][am] = a0.w;
    As[akq + 4][am] = a1.x; As[akq + 5][am] = a1.y;
    As[akq + 6][am] = a1.z; As[akq + 7][am] = a1.w;
    Bs[bk + 0][bn] = b0.x; Bs[bk + 1][bn] = b0.y;
    Bs[bk + 2][bn] = b0.z; Bs[bk + 3][bn] = b0.w;
    __syncthreads();
#pragma unroll
    for (int kk = 0; kk < 16; ++kk) {
      float4 x0 = *(const float4*)&As[kk][tm * 8];
      float4 x1 = *(const float4*)&As[kk][tm * 8 + 4];
      float4 y0 = *(const float4*)&Bs[kk][tn * 4];
      float av[8] = {x0.x, x0.y, x0.z, x0.w, x1.x, x1.y, x1.z, x1.w};
      float bv[4] = {y0.x, y0.y, y0.z, y0.w};
#pragma unroll
      for (int i = 0; i < 8; ++i)
#pragma unroll
        for (int j = 0; j < 4; ++j) acc[i][j] += av[i] * bv[j];
    }
  }
#pragma unroll
  for (int i = 0; i < 8; ++i) {
    float4 o = make_float4(acc[i][0], acc[i][1], acc[i][2], acc[i][3]);
    *(float4*)&C[(size_t)(m0 + tm * 8 + i) * ldc + n0 + tn * 4] = o;
  }
}

// ---------------- conv halo save (before in-place conv) ----------------------
__global__ __launch_bounds__(256) void halo_kernel(const float* __restrict__ zx,
                                                   float* __restrict__ halo) {
  int idx = blockIdx.x * 256 + threadIdx.x;  // < 2*16*3*4224
  int ch = idx % 4224;
  int r = idx / 4224;
  int j = r % 3;
  int r2 = r / 3;
  int lc = r2 & 15, b = r2 >> 4;
  int l = lc * 128 - 3 + j;
  halo[idx] = (l < 0) ? 0.f : zx[(size_t)(b * 2048 + l) * DPROJ + 4096 + ch];
}

// ---------------- causal conv1d(4) + silu, in place on xBC slice -------------
__global__ __launch_bounds__(256) void conv_kernel(float* __restrict__ zx,
                                                   const float* __restrict__ halo,
                                                   const float* __restrict__ cw,
                                                   const float* __restrict__ cb) {
  int idx = blockIdx.x * 256 + threadIdx.x;  // < 2*16*4224
  int ch = idx % 4224;
  int r = idx / 4224;  // b*16+lc
  int lc = r & 15, b = r >> 4;
  float w0 = cw[ch * 4 + 0], w1 = cw[ch * 4 + 1], w2 = cw[ch * 4 + 2],
        w3 = cw[ch * 4 + 3];
  float bias = cb[ch];
  const float* hp = halo + (size_t)r * 3 * 4224 + ch;
  float x3 = hp[0], x2 = hp[4224], x1 = hp[2 * 4224];
  size_t base = (size_t)(b * 2048 + lc * 128) * DPROJ + 4096 + ch;
  for (int i = 0; i < 128; ++i) {
    float x0 = zx[base];
    float v = bias + w0 * x3 + w1 * x2 + w2 * x1 + w3 * x0;
    v = v / (1.f + __expf(-v));  // silu
    zx[base] = v;
    x3 = x2; x2 = x1; x1 = x0;
    base += DPROJ;
  }
}

// ---------------- dt softplus + per-chunk cumsum of dt*A ---------------------
__global__ __launch_bounds__(256) void dtacum_kernel(
    const float* __restrict__ dtraw, const float* __restrict__ dt_bias,
    const float* __restrict__ A_log, float* __restrict__ dtb,
    float* __restrict__ acu) {
  int bid = blockIdx.x;  // (b*64+h)*8 + c
  int c = bid & 7, h = (bid >> 3) & 63, b = bid >> 9;
  int s = threadIdx.x;
  int tok = b * 2048 + c * 256 + s;
  float raw = dtraw[(size_t)tok * 64 + h] + dt_bias[h];
  float dtv = (raw > 20.f) ? raw : log1pf(expf(raw));
  float A = -expf(A_log[h]);
  __shared__ float sc[256];
  sc[s] = dtv * A;
  __syncthreads();
  for (int off = 1; off < 256; off <<= 1) {
    float v = (s >= off) ? sc[s - off] : 0.f;
    __syncthreads();
    sc[s] += v;
    __syncthreads();
  }
  int o = (b * 64 + h) * 2048 + c * 256 + s;
  dtb[o] = dtv;
  acu[o] = sc[s];
}

// ---------------- CB^T per (b,c): cbt[s][l] = sum_n C[l,n]*B[s,n] ------------
__global__ __launch_bounds__(256) void cbt_kernel(const float* __restrict__ zx,
                                                  float* __restrict__ cbt) {
  __shared__ float cl[256][33];
  __shared__ float blds[16][32];
  int bid = blockIdx.x;  // (b*8+c)*16 + sb
  int sb = bid & 15, c = (bid >> 4) & 7, b = bid >> 7;
  int t = threadIdx.x;
  int tok0 = b * 2048 + c * 256;
  float acc[16];
#pragma unroll
  for (int i = 0; i < 16; ++i) acc[i] = 0.f;
  for (int nh = 0; nh < 2; ++nh) {
    __syncthreads();
    for (int it = 0; it < 32; ++it) {
      int e = it * 256 + t;
      int row = e >> 5, n = e & 31;
      cl[row][n] = zx[(size_t)(tok0 + row) * DPROJ + 8256 + nh * 32 + n];
    }
    for (int it = 0; it < 2; ++it) {
      int e = it * 256 + t;
      int row = e >> 5, n = e & 31;
      blds[row][n] =
          zx[(size_t)(tok0 + sb * 16 + row) * DPROJ + 8192 + nh * 32 + n];
    }
    __syncthreads();
    for (int n = 0; n < 32; ++n) {
      float cv = cl[t][n];
#pragma unroll
      for (int s2 = 0; s2 < 16; ++s2) acc[s2] += cv * blds[s2][n];
    }
  }
#pragma unroll
  for (int s2 = 0; s2 < 16; ++s2)
    cbt[((size_t)(b * 8 + c) * 256 + sb * 16 + s2) * 256 + t] = acc[s2];
}

// ---------------- C transpose: cct[b][c][n][l] -------------------------------
__global__ __launch_bounds__(256) void ctrans_kernel(const float* __restrict__ zx,
                                                     float* __restrict__ cct) {
  int idx = blockIdx.x * 256 + threadIdx.x;  // ((b*8+c)*64+n)*256 + l
  int l = idx & 255, n = (idx >> 8) & 63, bc = idx >> 14;
  int b = bc >> 3, c = bc & 7;
  cct[idx] = zx[(size_t)(b * 2048 + c * 256 + l) * DPROJ + 8256 + n];
}

// ---------------- chunk states: st[p][n] = sum_s B[s,n] w[s] x[s,p] ----------
__global__ __launch_bounds__(256) void states_kernel(
    const float* __restrict__ zx, const float* __restrict__ dtb,
    const float* __restrict__ acu, float* __restrict__ st) {
  __shared__ __align__(16) float xl[64 * 64];
  __shared__ __align__(16) float bl[64 * 64];
  __shared__ float wl[256];
  int bid = blockIdx.x;  // (b*8+c)*64 + h
  int h = bid & 63, c = (bid >> 6) & 7, b = bid >> 9;
  int t = threadIdx.x;
  int tok0 = b * 2048 + c * 256;
  int bh = (b * 64 + h) * 2048 + c * 256;
  {
    float aend = acu[bh + 255];
    wl[t] = __expf(aend - acu[bh + t]) * dtb[bh + t];
  }
  int n = t & 63, p0 = (t >> 6) * 16;
  float acc[16];
#pragma unroll
  for (int i = 0; i < 16; ++i) acc[i] = 0.f;
  for (int sch = 0; sch < 4; ++sch) {
    __syncthreads();
    for (int it = 0; it < 4; ++it) {
      int e = it * 1024 + t * 4;
      int s = e >> 6, p = e & 63;
      *(float4*)&xl[e] = *(const float4*)&zx[(size_t)(tok0 + sch * 64 + s) * DPROJ +
                                             4096 + h * 64 + p];
      *(float4*)&bl[e] =
          *(const float4*)&zx[(size_t)(tok0 + sch * 64 + s) * DPROJ + 8192 + p];
    }
    __syncthreads();
    for (int s = 0; s < 64; ++s) {
      float bw = bl[s * 64 + n] * wl[sch * 64 + s];
#pragma unroll
      for (int i = 0; i < 16; ++i) acc[i] += bw * xl[s * 64 + p0 + i];
    }
  }
  float* out = st + ((size_t)(b * 8 + c) * 64 + h) * 4096;
#pragma unroll
  for (int i = 0; i < 16; ++i) out[(p0 + i) * 64 + n] = acc[i];
}

// ---------------- inter-chunk scan (in place states -> prev_states) ---------
__global__ __launch_bounds__(256) void chunkscan_kernel(
    const float* __restrict__ acu, float* __restrict__ st) {
  int bid = blockIdx.x;  // (b*64+h)*16 + pc
  int pc = bid & 15, h = (bid >> 4) & 63, b = bid >> 10;
  int pn = pc * 256 + threadIdx.x;
  int abase = (b * 64 + h) * 2048;
  float run = 0.f;
  for (int c = 0; c < 8; ++c) {
    size_t idx = ((size_t)(b * 8 + c) * 64 + h) * 4096 + pn;
    float s = st[idx];
    st[idx] = run;
    float ach = acu[abase + c * 256 + 255];
    run = run * __expf(ach) + s;
  }
}

// ---------------- Y = (CB∘L)·(x·dt) + diag(e^Acum)·C·prev^T + D·x ------------
__global__ __launch_bounds__(256) void ydiag_kernel(
    const float* __restrict__ zx, const float* __restrict__ dtb,
    const float* __restrict__ acu, const float* __restrict__ cbt,
    const float* __restrict__ cct, const float* __restrict__ st,
    const float* __restrict__ Dp, float* __restrict__ yb) {
  __shared__ __align__(16) float xa[320][36];
  __shared__ float acs[256];
  __shared__ float dts[256];
  int bid = blockIdx.x;  // (b*8+c)*64 + h
  int h = bid & 63, c = (bid >> 6) & 7, b = bid >> 9;
  int l = threadIdx.x;
  int tok0 = b * 2048 + c * 256;
  int bh = (b * 64 + h) * 2048 + c * 256;
  acs[l] = acu[bh + l];
  dts[l] = dtb[bh + l];
  __syncthreads();
  float Al = acs[l];
  float expAl = __expf(Al);
  float Dh = Dp[h];
  const float* cbt_b = cbt + (size_t)(b * 8 + c) * 256 * 256;
  const float* cct_b = cct + (size_t)(b * 8 + c) * 64 * 256;
  const float* st_b = st + ((size_t)(b * 8 + c) * 64 + h) * 4096;
  const int smax = l | 63;  // wave-uniform triangular cutoff

  for (int half = 0; half < 2; ++half) {
    const int p0 = half * 32;
    __syncthreads();
    for (int it = 0; it < 32; ++it) {
      int e = it * 256 + threadIdx.x;
      int s = e >> 5, pp = e & 31;
      xa[s][pp] = zx[(size_t)(tok0 + s) * DPROJ + 4096 + h * 64 + p0 + pp];
    }
    for (int it = 0; it < 8; ++it) {
      int e = it * 256 + threadIdx.x;
      int n = e & 63, pp = e >> 6;
      xa[256 + n][pp] = st_b[(p0 + pp) * 64 + n];
    }
    __syncthreads();
    float acc[32];
#pragma unroll
    for (int i = 0; i < 32; ++i) acc[i] = 0.f;
    for (int s = 0; s <= smax; ++s) {
      float w = 0.f;
      if (s <= l) w = cbt_b[s * 256 + l] * __expf(Al - acs[s]) * dts[s];
#pragma unroll
      for (int q = 0; q < 8; ++q) {
        float4 xv = *(const float4*)&xa[s][q * 4];
        acc[4 * q + 0] += w * xv.x;
        acc[4 * q + 1] += w * xv.y;
        acc[4 * q + 2] += w * xv.z;
        acc[4 * q + 3] += w * xv.w;
      }
    }
    for (int n = 0; n < 64; ++n) {
      float w = cct_b[n * 256 + l] * expAl;
#pragma unroll
      for (int q = 0; q < 8; ++q) {
        float4 xv = *(const float4*)&xa[256 + n][q * 4];
        acc[4 * q + 0] += w * xv.x;
        acc[4 * q + 1] += w * xv.y;
        acc[4 * q + 2] += w * xv.z;
        acc[4 * q + 3] += w * xv.w;
      }
    }
#pragma unroll
    for (int pp = 0; pp < 32; ++pp) acc[pp] += Dh * xa[l][pp];
    __syncthreads();
#pragma unroll
    for (int pp = 0; pp < 32; ++pp) xa[l][pp] = acc[pp];
    __syncthreads();
    for (int it = 0; it < 32; ++it) {
      int e = it * 256 + threadIdx.x;
      int s = e >> 5, pp = e & 31;
      yb[(size_t)(bh + s) * 64 + p0 + pp] = xa[s][pp];
    }
  }
}

// ---------------- gate + RMSNorm -> bf16 activations (aliases zx z-slice) ----
__global__ __launch_bounds__(256) void gatenorm_kernel(
    const float* zx, const float* __restrict__ nw,
    const float* __restrict__ yb, short* ybh) {
  int tok = blockIdx.x;
  int b = tok >> 11, l = tok & 2047;
  int t = threadIdx.x;
  float g[16];
  float ss = 0.f;
#pragma unroll
  for (int i = 0; i < 16; ++i) {
    int d = i * 256 + t;
    int h = d >> 6, p = d & 63;
    float yv = yb[((size_t)(b * 64 + h) * 2048 + l) * 64 + p];
    float zv = zx[(size_t)tok * DPROJ + d];
    float gv = yv * (zv / (1.f + __expf(-zv)));
    g[i] = gv;
    ss += gv * gv;
  }
  for (int off = 32; off > 0; off >>= 1) ss += __shfl_down(ss, off);
  __shared__ float red[4];
  int wid = t >> 6, lane = t & 63;
  if (lane == 0) red[wid] = ss;
  __syncthreads();  // all zx reads complete before aliased writes below
  float tot = red[0] + red[1] + red[2] + red[3];
  float scale = rsqrtf(tot * (1.f / 4096.f) + 1e-5f);
#pragma unroll
  for (int i = 0; i < 16; ++i) {
    int d = i * 256 + t;
    ybh[(size_t)tok * 16768 + d] = f2bf(g[i] * scale * nw[d]);
  }
}

extern "C" void kernel_launch(void* const* d_in, const int* in_sizes, int n_in,
                              void* d_out, int out_size, void* d_ws,
                              size_t ws_size, hipStream_t stream) {
  const float* u = (const float*)d_in[0];
  const float* W_in = (const float*)d_in[1];
  const float* conv_w = (const float*)d_in[2];
  const float* conv_b = (const float*)d_in[3];
  const float* dt_bias = (const float*)d_in[4];
  const float* A_log = (const float*)d_in[5];
  const float* Dp = (const float*)d_in[6];
  const float* norm_w = (const float*)d_in[7];
  const float* W_out = (const float*)d_in[8];
  float* out = (float*)d_out;
  float* ws = (float*)d_ws;

  float* zx = ws + ZX_OFF;
  float* dtb = ws + DTB_OFF;
  float* acu = ws + ACU_OFF;
  float* cbtb = ws + CBT_OFF;
  float* cct = ws + CCT_OFF;
  float* st = ws + ST_OFF;
  float* yb = ws + YB_OFF;
  float* halo = ws + HALO_OFF;
  float* dtraw = ws + DTRAW_OFF;
  short* u16 = (short*)(ws + U16_OFF);
  short* win16 = (short*)(ws + WIN16_OFF);
  short* wout16 = (short*)(ws + WOUT16_OFF);
  short* ybh = (short*)zx;  // bf16 normed activations over dead z-slice

  // 0. casts for in_proj
  cast_bf16_kernel<<<4096, 256, 0, stream>>>(u, u16, 1048576);
  cast_bf16_kernel<<<8384, 256, 0, stream>>>(W_in, win16, 2146304);
  // 1. in_proj (bf16 MFMA): zx = u @ W_in^T   (4096 x 8384, K=2048)
  gemm_bf16<<<dim3(66, 32), 256, 0, stream>>>(u16, 2048, win16, 2048, zx, DPROJ,
                                              2048, DPROJ);
  // 1b. dt columns in fp32 (64 cols, exp-sensitive): dtraw = u @ W_in[8320:]^T
  gemm_f32_nt<<<dim3(1, 32), 256, 0, stream>>>(u, W_in + 8320ul * 2048, dtraw,
                                               2048, 64);
  // 2. conv halo save, then in-place conv+silu on xBC slice
  halo_kernel<<<1584, 256, 0, stream>>>(zx, halo);
  conv_kernel<<<528, 256, 0, stream>>>(zx, halo, conv_w, conv_b);
  // 3. dt softplus + per-chunk cumsum(dt*A)
  dtacum_kernel<<<1024, 256, 0, stream>>>(dtraw, dt_bias, A_log, dtb, acu);
  // 4. shared C·B^T and C^T per (b,c)
  cbt_kernel<<<256, 256, 0, stream>>>(zx, cbtb);
  ctrans_kernel<<<1024, 256, 0, stream>>>(zx, cct);
  // 5. chunk states, then inter-chunk scan (in place -> prev_states)
  states_kernel<<<1024, 256, 0, stream>>>(zx, dtb, acu, st);
  chunkscan_kernel<<<2048, 256, 0, stream>>>(acu, st);
  // 6. Y (diag + off + D term) -> yb
  ydiag_kernel<<<1024, 256, 0, stream>>>(zx, dtb, acu, cbtb, cct, st, Dp, yb);
  // 7. W_out cast (dtb..st regions dead now)
  cast_bf16_kernel<<<4096, 256, 0, stream>>>(W_out, wout16, 1048576);
  // 8. gate + RMSNorm -> bf16 ybh (aliases zx z-slice; reads precede writes)
  gatenorm_kernel<<<4096, 256, 0, stream>>>(zx, norm_w, yb, ybh);
  // 9. out_proj (bf16 MFMA): out = ybh @ W_out^T  (4096 x 2048, K=4096)
  gemm_bf16<<<dim3(16, 32), 256, 0, stream>>>(ybh, 16768, wout16, 4096, out,
                                              2048, 4096, 2048);
}

// Round 3
// 784.807 us; speedup vs baseline: 4.5199x; 1.4445x over previous
//
#include <hip/hip_runtime.h>
#include <hip/hip_bf16.h>
#include <cstdint>

// Problem constants
#define DPROJ  8384

typedef __attribute__((ext_vector_type(8))) short short8;
typedef __attribute__((ext_vector_type(4))) short sh4;
typedef __attribute__((ext_vector_type(4))) float f32x4;

// workspace offsets (float units)
#define ZX_OFF     0ul
#define DTB_OFF    34340864ul   // [b][h][l] dt (softplus'd)
#define ACU_OFF    34603008ul   // [b][h][l] within-chunk cumsum of dt*A
#define CBT_OFF    34865152ul   // [b][c][s][l]  (C·B^T)^T
#define CCT_OFF    35913728ul   // [b][c][n][l]  C transposed
#define ST_OFF     36175872ul   // [b][c][h][p][n] states -> prev_states
#define YB_OFF     40370176ul   // [b][h][l][p] ssd output
#define HALO_OFF   57147392ul   // [b][lc][3][ch] conv halo
// aliases (disjoint lifetimes):
#define U16_OFF    40370176ul   // bf16 u  (dead before ydiag writes yb)
#define WIN16_OFF  48758784ul   // bf16 W_in (dead before halo written)
#define WOUT16_OFF 34340864ul   // bf16 W_out (written after ydiag frees dtb)
#define DTRAW_OFF  36175872ul   // fp32 dt raw [tok][64] (dead before states)

__device__ __forceinline__ short f2bf(float x) {
  union { float f; uint32_t u; } v{x};
  uint32_t r = (v.u + 0x7fff + ((v.u >> 16) & 1)) >> 16;
  return (short)r;
}
__device__ __forceinline__ float bf2f(short s) {
  union { uint32_t u; float f; } v;
  v.u = ((uint32_t)(uint16_t)s) << 16;
  return v.f;
}

// ---------------- fp32 -> bf16 cast (8 elems/thread) -------------------------
__global__ __launch_bounds__(256) void cast_bf16_kernel(
    const float* __restrict__ in, short* __restrict__ out, int n8) {
  int i = blockIdx.x * 256 + threadIdx.x;
  if (i >= n8) return;
  const float4* p = (const float4*)(in + (size_t)i * 8);
  float4 a = p[0], b = p[1];
  short8 o;
  o[0] = f2bf(a.x); o[1] = f2bf(a.y); o[2] = f2bf(a.z); o[3] = f2bf(a.w);
  o[4] = f2bf(b.x); o[5] = f2bf(b.y); o[6] = f2bf(b.z); o[7] = f2bf(b.w);
  *(short8*)(out + (size_t)i * 8) = o;
}

// ---------------- bf16 MFMA GEMM (NT): C[M][N] = A[M][K] * B[N][K]^T ---------
__device__ __forceinline__ void gload16(const void* g, const void* l) {
  __builtin_amdgcn_global_load_lds(
      (const __attribute__((address_space(1))) void*)g,
      (__attribute__((address_space(3))) void*)l, 16, 0, 0);
}

__global__ __launch_bounds__(256) void gemm_bf16(
    const short* __restrict__ A, int lda, const short* __restrict__ B, int ldb,
    float* __restrict__ C, int ldc, int K, int Nvalid) {
  __shared__ __align__(16) short As[128 * 32];
  __shared__ __align__(16) short Bs[128 * 32];
  const int t = threadIdx.x;
  const int w = t >> 6, lane = t & 63;
  const int m0 = blockIdx.y * 128, n0 = blockIdx.x * 128;
  const int wr = (w >> 1) * 64, wc = (w & 1) * 64;
  const int arow = t >> 2, kk = (t & 3) * 8;
  const int fr = lane & 15, fk = (lane >> 4) * 8;
  int br0 = n0 + arow;       if (br0 > Nvalid - 1) br0 = Nvalid - 1;
  int br1 = n0 + 64 + arow;  if (br1 > Nvalid - 1) br1 = Nvalid - 1;
  const short* pa0 = A + (size_t)(m0 + arow) * lda + kk;
  const short* pa1 = A + (size_t)(m0 + 64 + arow) * lda + kk;
  const short* pb0 = B + (size_t)br0 * ldb + kk;
  const short* pb1 = B + (size_t)br1 * ldb + kk;
  short* la = As + w * 512;
  short* lb = Bs + w * 512;
  f32x4 acc[4][4];
#pragma unroll
  for (int i = 0; i < 4; ++i)
#pragma unroll
    for (int j = 0; j < 4; ++j) acc[i][j] = (f32x4){0.f, 0.f, 0.f, 0.f};

  for (int k0 = 0; k0 < K; k0 += 32) {
    gload16(pa0 + k0, la);
    gload16(pa1 + k0, la + 2048);
    gload16(pb0 + k0, lb);
    gload16(pb1 + k0, lb + 2048);
    __syncthreads();
    short8 af[4], bg[4];
#pragma unroll
    for (int i = 0; i < 4; ++i) {
      af[i] = *(const short8*)&As[(wr + i * 16 + fr) * 32 + fk];
      bg[i] = *(const short8*)&Bs[(wc + i * 16 + fr) * 32 + fk];
    }
#pragma unroll
    for (int i = 0; i < 4; ++i)
#pragma unroll
      for (int j = 0; j < 4; ++j)
        acc[i][j] = __builtin_amdgcn_mfma_f32_16x16x32_bf16(af[i], bg[j],
                                                            acc[i][j], 0, 0, 0);
    __syncthreads();
  }
#pragma unroll
  for (int i = 0; i < 4; ++i) {
    const int row = m0 + wr + i * 16 + (lane >> 4) * 4;
#pragma unroll
    for (int j = 0; j < 4; ++j) {
      const int col = n0 + wc + j * 16 + fr;
      if (col < Nvalid) {
#pragma unroll
        for (int r = 0; r < 4; ++r)
          C[(size_t)(row + r) * ldc + col] = acc[i][j][r];
      }
    }
  }
}

// ---------------- small fp32 GEMM (NT) for dt columns ------------------------
__global__ __launch_bounds__(256) void gemm_f32_nt(const float* __restrict__ A,
                                                   const float* __restrict__ Bw,
                                                   float* __restrict__ C, int K,
                                                   int ldc) {
  __shared__ __align__(16) float As[16][128];
  __shared__ __align__(16) float Bs[16][64];
  const int tid = threadIdx.x;
  const int m0 = blockIdx.y * 128, n0 = blockIdx.x * 64;
  const int tm = tid & 15, tn = tid >> 4;
  const int am = tid >> 1;
  const int akq = (tid & 1) * 8;
  const int bn = tid >> 2;
  const int bk = (tid & 3) * 4;
  float acc[8][4];
#pragma unroll
  for (int i = 0; i < 8; ++i)
#pragma unroll
    for (int j = 0; j < 4; ++j) acc[i][j] = 0.f;

  for (int k0 = 0; k0 < K; k0 += 16) {
    const float* ap = A + (size_t)(m0 + am) * K + k0 + akq;
    float4 a0 = *(const float4*)ap;
    float4 a1 = *(const float4*)(ap + 4);
    float4 b0 = *(const float4*)(Bw + (size_t)(n0 + bn) * K + k0 + bk);
    __syncthreads();
    As[akq + 0][am] = a0.x; As[akq + 1][am] = a0.y;
    As[akq + 2][am] = a0.z; As[akq + 3][am] = a0.w;
    As[akq + 4][am] = a1.x; As[akq + 5][am] = a1.y;
    As[akq + 6][am] = a1.z; As[akq + 7][am] = a1.w;
    Bs[bk + 0][bn] = b0.x; Bs[bk + 1][bn] = b0.y;
    Bs[bk + 2][bn] = b0.z; Bs[bk + 3][bn] = b0.w;
    __syncthreads();
#pragma unroll
    for (int kk = 0; kk < 16; ++kk) {
      float4 x0 = *(const float4*)&As[kk][tm * 8];
      float4 x1 = *(const float4*)&As[kk][tm * 8 + 4];
      float4 y0 = *(const float4*)&Bs[kk][tn * 4];
      float av[8] = {x0.x, x0.y, x0.z, x0.w, x1.x, x1.y, x1.z, x1.w};
      float bv[4] = {y0.x, y0.y, y0.z, y0.w};
#pragma unroll
      for (int i = 0; i < 8; ++i)
#pragma unroll
        for (int j = 0; j < 4; ++j) acc[i][j] += av[i] * bv[j];
    }
  }
#pragma unroll
  for (int i = 0; i < 8; ++i) {
    float4 o = make_float4(acc[i][0], acc[i][1], acc[i][2], acc[i][3]);
    *(float4*)&C[(size_t)(m0 + tm * 8 + i) * ldc + n0 + tn * 4] = o;
  }
}

// ---------------- conv halo save (before in-place conv) ----------------------
__global__ __launch_bounds__(256) void halo_kernel(const float* __restrict__ zx,
                                                   float* __restrict__ halo) {
  int idx = blockIdx.x * 256 + threadIdx.x;
  int ch = idx % 4224;
  int r = idx / 4224;
  int j = r % 3;
  int r2 = r / 3;
  int lc = r2 & 15, b = r2 >> 4;
  int l = lc * 128 - 3 + j;
  halo[idx] = (l < 0) ? 0.f : zx[(size_t)(b * 2048 + l) * DPROJ + 4096 + ch];
}

// ---------------- causal conv1d(4) + silu, in place on xBC slice -------------
__global__ __launch_bounds__(256) void conv_kernel(float* __restrict__ zx,
                                                   const float* __restrict__ halo,
                                                   const float* __restrict__ cw,
                                                   const float* __restrict__ cb) {
  int idx = blockIdx.x * 256 + threadIdx.x;
  int ch = idx % 4224;
  int r = idx / 4224;
  int lc = r & 15, b = r >> 4;
  float w0 = cw[ch * 4 + 0], w1 = cw[ch * 4 + 1], w2 = cw[ch * 4 + 2],
        w3 = cw[ch * 4 + 3];
  float bias = cb[ch];
  const float* hp = halo + (size_t)r * 3 * 4224 + ch;
  float x3 = hp[0], x2 = hp[4224], x1 = hp[2 * 4224];
  size_t base = (size_t)(b * 2048 + lc * 128) * DPROJ + 4096 + ch;
  for (int i = 0; i < 128; ++i) {
    float x0 = zx[base];
    float v = bias + w0 * x3 + w1 * x2 + w2 * x1 + w3 * x0;
    v = v / (1.f + __expf(-v));
    zx[base] = v;
    x3 = x2; x2 = x1; x1 = x0;
    base += DPROJ;
  }
}

// ---------------- dt softplus + per-chunk cumsum of dt*A ---------------------
__global__ __launch_bounds__(256) void dtacum_kernel(
    const float* __restrict__ dtraw, const float* __restrict__ dt_bias,
    const float* __restrict__ A_log, float* __restrict__ dtb,
    float* __restrict__ acu) {
  int bid = blockIdx.x;
  int c = bid & 7, h = (bid >> 3) & 63, b = bid >> 9;
  int s = threadIdx.x;
  int tok = b * 2048 + c * 256 + s;
  float raw = dtraw[(size_t)tok * 64 + h] + dt_bias[h];
  float dtv = (raw > 20.f) ? raw : log1pf(expf(raw));
  float A = -expf(A_log[h]);
  __shared__ float sc[256];
  sc[s] = dtv * A;
  __syncthreads();
  for (int off = 1; off < 256; off <<= 1) {
    float v = (s >= off) ? sc[s - off] : 0.f;
    __syncthreads();
    sc[s] += v;
    __syncthreads();
  }
  int o = (b * 64 + h) * 2048 + c * 256 + s;
  dtb[o] = dtv;
  acu[o] = sc[s];
}

// ---------------- CB^T per (b,c): cbt[s][l] = sum_n C[l,n]*B[s,n] ------------
__global__ __launch_bounds__(256) void cbt_kernel(const float* __restrict__ zx,
                                                  float* __restrict__ cbt) {
  __shared__ float cl[256][33];
  __shared__ float blds[16][32];
  int bid = blockIdx.x;
  int sb = bid & 15, c = (bid >> 4) & 7, b = bid >> 7;
  int t = threadIdx.x;
  int tok0 = b * 2048 + c * 256;
  float acc[16];
#pragma unroll
  for (int i = 0; i < 16; ++i) acc[i] = 0.f;
  for (int nh = 0; nh < 2; ++nh) {
    __syncthreads();
    for (int it = 0; it < 32; ++it) {
      int e = it * 256 + t;
      int row = e >> 5, n = e & 31;
      cl[row][n] = zx[(size_t)(tok0 + row) * DPROJ + 8256 + nh * 32 + n];
    }
    for (int it = 0; it < 2; ++it) {
      int e = it * 256 + t;
      int row = e >> 5, n = e & 31;
      blds[row][n] =
          zx[(size_t)(tok0 + sb * 16 + row) * DPROJ + 8192 + nh * 32 + n];
    }
    __syncthreads();
    for (int n = 0; n < 32; ++n) {
      float cv = cl[t][n];
#pragma unroll
      for (int s2 = 0; s2 < 16; ++s2) acc[s2] += cv * blds[s2][n];
    }
  }
#pragma unroll
  for (int s2 = 0; s2 < 16; ++s2)
    cbt[((size_t)(b * 8 + c) * 256 + sb * 16 + s2) * 256 + t] = acc[s2];
}

// ---------------- C transpose: cct[b][c][n][l] -------------------------------
__global__ __launch_bounds__(256) void ctrans_kernel(const float* __restrict__ zx,
                                                     float* __restrict__ cct) {
  int idx = blockIdx.x * 256 + threadIdx.x;
  int l = idx & 255, n = (idx >> 8) & 63, bc = idx >> 14;
  int b = bc >> 3, c = bc & 7;
  cct[idx] = zx[(size_t)(b * 2048 + c * 256 + l) * DPROJ + 8256 + n];
}

// ---------------- states (MFMA): st[p][n] = sum_s x[s,p] B[s,n] w[s] ---------
__global__ __launch_bounds__(256) void states_mfma(
    const float* __restrict__ zx, const float* __restrict__ dtb,
    const float* __restrict__ acu, float* __restrict__ st) {
  __shared__ __align__(16) short As2[64][136];  // X^T [p][k]
  __shared__ __align__(16) short Bs2[64][136];  // (B·w)^T [n][k]
  __shared__ float wl[256];
  int bid = blockIdx.x;  // (b*8+c)*64 + h
  int h = bid & 63, c = (bid >> 6) & 7, b = bid >> 9;
  int t = threadIdx.x;
  int w = t >> 6, lane = t & 63;
  int tok0 = b * 2048 + c * 256;
  int bh = (b * 64 + h) * 2048 + c * 256;
  {
    float aend = acu[bh + 255];
    wl[t] = __expf(aend - acu[bh + t]) * dtb[bh + t];
  }
  __syncthreads();
  const float* xbase = zx + (size_t)tok0 * DPROJ + 4096 + h * 64;
  const float* bbase = zx + (size_t)tok0 * DPROJ + 8192;
  const int fr = lane & 15, fko = (lane >> 4) * 8;
  const int wi = (w >> 1) * 32, wj = (w & 1) * 32;
  f32x4 acc[2][2];
#pragma unroll
  for (int i = 0; i < 2; ++i)
#pragma unroll
    for (int j = 0; j < 2; ++j) acc[i][j] = (f32x4){0.f, 0.f, 0.f, 0.f};

  for (int ph = 0; ph < 2; ++ph) {
    const int kb = ph * 128;
    if (ph) __syncthreads();
    for (int it = 0; it < 8; ++it) {
      int idx = it * 256 + t;
      int p = idx & 63, kg = idx >> 6;  // kg 0..31
      int k = kb + kg * 4;
      const float* xp = xbase + (size_t)k * DPROJ + p;
      const float* bp = bbase + (size_t)k * DPROJ + p;
      sh4 oa, ob;
#pragma unroll
      for (int r = 0; r < 4; ++r) {
        oa[r] = f2bf(xp[(size_t)r * DPROJ]);
        ob[r] = f2bf(bp[(size_t)r * DPROJ] * wl[k + r]);
      }
      *(sh4*)&As2[p][kg * 4] = oa;
      *(sh4*)&Bs2[p][kg * 4] = ob;
    }
    __syncthreads();
#pragma unroll
    for (int kk0 = 0; kk0 < 128; kk0 += 32) {
      short8 af[2], bg[2];
#pragma unroll
      for (int i = 0; i < 2; ++i) {
        af[i] = *(const short8*)&As2[wi + i * 16 + fr][kk0 + fko];
        bg[i] = *(const short8*)&Bs2[wj + i * 16 + fr][kk0 + fko];
      }
#pragma unroll
      for (int i = 0; i < 2; ++i)
#pragma unroll
        for (int j = 0; j < 2; ++j)
          acc[i][j] = __builtin_amdgcn_mfma_f32_16x16x32_bf16(af[i], bg[j],
                                                              acc[i][j], 0, 0, 0);
    }
  }
  float* out = st + ((size_t)(b * 8 + c) * 64 + h) * 4096;
  const int rq = (lane >> 4) * 4;
#pragma unroll
  for (int i = 0; i < 2; ++i) {
    int p0 = wi + i * 16 + rq;
#pragma unroll
    for (int j = 0; j < 2; ++j) {
      int n = wj + j * 16 + fr;
#pragma unroll
      for (int r = 0; r < 4; ++r)
        out[(size_t)(p0 + r) * 64 + n] = acc[i][j][r];
    }
  }
}

// ---------------- inter-chunk scan (in place states -> prev_states) ---------
__global__ __launch_bounds__(256) void chunkscan_kernel(
    const float* __restrict__ acu, float* __restrict__ st) {
  int bid = blockIdx.x;
  int pc = bid & 15, h = (bid >> 4) & 63, b = bid >> 10;
  int pn = pc * 256 + threadIdx.x;
  int abase = (b * 64 + h) * 2048;
  float run = 0.f;
  for (int c = 0; c < 8; ++c) {
    size_t idx = ((size_t)(b * 8 + c) * 64 + h) * 4096 + pn;
    float s = st[idx];
    st[idx] = run;
    float ach = acu[abase + c * 256 + 255];
    run = run * __expf(ach) + s;
  }
}

// ---------------- Y (MFMA): M=256 l, N=64 p, K=320 (256 s + 64 n) ------------
__global__ __launch_bounds__(256) void ydiag_mfma(
    const float* __restrict__ zx, const float* __restrict__ dtb,
    const float* __restrict__ acu, const float* __restrict__ cbt,
    const float* __restrict__ cct, const float* __restrict__ st,
    const float* __restrict__ Dp, float* __restrict__ yb) {
  __shared__ __align__(16) short Xs[64][328];  // [p][k]: k<256 x, k>=256 prev
  __shared__ float acs[256];
  __shared__ float dts[256];
  int bid = blockIdx.x;  // (b*8+c)*64 + h
  int h = bid & 63, c = (bid >> 6) & 7, b = bid >> 9;
  int t = threadIdx.x;
  int w = t >> 6, lane = t & 63;
  int tok0 = b * 2048 + c * 256;
  int bh = (b * 64 + h) * 2048 + c * 256;
  acs[t] = acu[bh + t];
  dts[t] = dtb[bh + t];
  const float* xbase = zx + (size_t)tok0 * DPROJ + 4096 + h * 64;
  const float* st_b = st + ((size_t)(b * 8 + c) * 64 + h) * 4096;
  // stage x^T (bf16): Xs[p][k] = x[tok0+k][p]
  for (int it = 0; it < 16; ++it) {
    int idx = it * 256 + t;
    int p = idx & 63, kg = idx >> 6;  // kg 0..63
    const float* xp = xbase + (size_t)(kg * 4) * DPROJ + p;
    sh4 o;
    o[0] = f2bf(xp[0]);
    o[1] = f2bf(xp[DPROJ]);
    o[2] = f2bf(xp[2 * DPROJ]);
    o[3] = f2bf(xp[3 * DPROJ]);
    *(sh4*)&Xs[p][kg * 4] = o;
  }
  // stage prev^T: Xs[p][256+n] = prev[n][p] = st[p][n]
  for (int it = 0; it < 4; ++it) {
    int idx = it * 256 + t;
    int ng = idx & 15, p = idx >> 4;
    float4 v = *(const float4*)&st_b[p * 64 + ng * 4];
    sh4 o;
    o[0] = f2bf(v.x); o[1] = f2bf(v.y); o[2] = f2bf(v.z); o[3] = f2bf(v.w);
    *(sh4*)&Xs[p][256 + ng * 4] = o;
  }
  __syncthreads();

  const int fr = lane & 15, fko = (lane >> 4) * 8;
  const int wr = w * 64;
  float Al[4], eAl[4];
#pragma unroll
  for (int i = 0; i < 4; ++i) {
    Al[i] = acs[wr + i * 16 + fr];
    eAl[i] = __expf(Al[i]);
  }
  f32x4 acc[4][4];
#pragma unroll
  for (int i = 0; i < 4; ++i)
#pragma unroll
    for (int j = 0; j < 4; ++j) acc[i][j] = (f32x4){0.f, 0.f, 0.f, 0.f};

  const float* cbt_b = cbt + (size_t)(b * 8 + c) * 65536;
  const float* cct_b = cct + (size_t)(b * 8 + c) * 16384;

  // masked decay part: s in [0, wr+64)
  for (int k0 = 0; k0 < wr + 64; k0 += 32) {
    short8 bg[4];
#pragma unroll
    for (int j = 0; j < 4; ++j)
      bg[j] = *(const short8*)&Xs[j * 16 + fr][k0 + fko];
#pragma unroll
    for (int i = 0; i < 4; ++i) {
      const int l = wr + i * 16 + fr;
      short8 af;
#pragma unroll
      for (int jj = 0; jj < 8; ++jj) {
        int s = k0 + fko + jj;
        float wv = 0.f;
        if (s <= l) wv = cbt_b[s * 256 + l] * __expf(Al[i] - acs[s]) * dts[s];
        af[jj] = f2bf(wv);
      }
#pragma unroll
      for (int j = 0; j < 4; ++j)
        acc[i][j] = __builtin_amdgcn_mfma_f32_16x16x32_bf16(af, bg[j],
                                                            acc[i][j], 0, 0, 0);
    }
  }
  // Y_off part: k in [256, 320) -> n = k-256
#pragma unroll
  for (int k0 = 256; k0 < 320; k0 += 32) {
    short8 bg[4];
#pragma unroll
    for (int j = 0; j < 4; ++j)
      bg[j] = *(const short8*)&Xs[j * 16 + fr][k0 + fko];
#pragma unroll
    for (int i = 0; i < 4; ++i) {
      const int l = wr + i * 16 + fr;
      short8 af;
#pragma unroll
      for (int jj = 0; jj < 8; ++jj) {
        int n = k0 - 256 + fko + jj;
        af[jj] = f2bf(cct_b[n * 256 + l] * eAl[i]);
      }
#pragma unroll
      for (int j = 0; j < 4; ++j)
        acc[i][j] = __builtin_amdgcn_mfma_f32_16x16x32_bf16(af, bg[j],
                                                            acc[i][j], 0, 0, 0);
    }
  }
  // epilogue: + D*x, store
  float Dh = Dp[h];
  const int rq = (lane >> 4) * 4;
#pragma unroll
  for (int i = 0; i < 4; ++i) {
    int l0 = wr + i * 16 + rq;
#pragma unroll
    for (int j = 0; j < 4; ++j) {
      int p = j * 16 + fr;
      sh4 x4 = *(const sh4*)&Xs[p][l0];
      f32x4 a = acc[i][j];
#pragma unroll
      for (int r = 0; r < 4; ++r)
        yb[(size_t)(bh + l0 + r) * 64 + p] = a[r] + Dh * bf2f(x4[r]);
    }
  }
}

// ---------------- gate + RMSNorm -> bf16 activations (aliases zx z-slice) ----
__global__ __launch_bounds__(256) void gatenorm_kernel(
    const float* zx, const float* __restrict__ nw,
    const float* __restrict__ yb, short* ybh) {
  int tok = blockIdx.x;
  int b = tok >> 11, l = tok & 2047;
  int t = threadIdx.x;
  float g[16];
  float ss = 0.f;
#pragma unroll
  for (int i = 0; i < 16; ++i) {
    int d = i * 256 + t;
    int h = d >> 6, p = d & 63;
    float yv = yb[((size_t)(b * 64 + h) * 2048 + l) * 64 + p];
    float zv = zx[(size_t)tok * DPROJ + d];
    float gv = yv * (zv / (1.f + __expf(-zv)));
    g[i] = gv;
    ss += gv * gv;
  }
  for (int off = 32; off > 0; off >>= 1) ss += __shfl_down(ss, off);
  __shared__ float red[4];
  int wid = t >> 6, lane = t & 63;
  if (lane == 0) red[wid] = ss;
  __syncthreads();
  float tot = red[0] + red[1] + red[2] + red[3];
  float scale = rsqrtf(tot * (1.f / 4096.f) + 1e-5f);
#pragma unroll
  for (int i = 0; i < 16; ++i) {
    int d = i * 256 + t;
    ybh[(size_t)tok * 16768 + d] = f2bf(g[i] * scale * nw[d]);
  }
}

extern "C" void kernel_launch(void* const* d_in, const int* in_sizes, int n_in,
                              void* d_out, int out_size, void* d_ws,
                              size_t ws_size, hipStream_t stream) {
  const float* u = (const float*)d_in[0];
  const float* W_in = (const float*)d_in[1];
  const float* conv_w = (const float*)d_in[2];
  const float* conv_b = (const float*)d_in[3];
  const float* dt_bias = (const float*)d_in[4];
  const float* A_log = (const float*)d_in[5];
  const float* Dp = (const float*)d_in[6];
  const float* norm_w = (const float*)d_in[7];
  const float* W_out = (const float*)d_in[8];
  float* out = (float*)d_out;
  float* ws = (float*)d_ws;

  float* zx = ws + ZX_OFF;
  float* dtb = ws + DTB_OFF;
  float* acu = ws + ACU_OFF;
  float* cbtb = ws + CBT_OFF;
  float* cct = ws + CCT_OFF;
  float* st = ws + ST_OFF;
  float* yb = ws + YB_OFF;
  float* halo = ws + HALO_OFF;
  float* dtraw = ws + DTRAW_OFF;
  short* u16 = (short*)(ws + U16_OFF);
  short* win16 = (short*)(ws + WIN16_OFF);
  short* wout16 = (short*)(ws + WOUT16_OFF);
  short* ybh = (short*)zx;

  // 0. casts for in_proj
  cast_bf16_kernel<<<4096, 256, 0, stream>>>(u, u16, 1048576);
  cast_bf16_kernel<<<8384, 256, 0, stream>>>(W_in, win16, 2146304);
  // 1. in_proj (bf16 MFMA): zx = u @ W_in^T
  gemm_bf16<<<dim3(66, 32), 256, 0, stream>>>(u16, 2048, win16, 2048, zx, DPROJ,
                                              2048, DPROJ);
  // 1b. dt columns in fp32 (exp-sensitive)
  gemm_f32_nt<<<dim3(1, 32), 256, 0, stream>>>(u, W_in + 8320ul * 2048, dtraw,
                                               2048, 64);
  // 2. conv halo, in-place conv+silu
  halo_kernel<<<1584, 256, 0, stream>>>(zx, halo);
  conv_kernel<<<528, 256, 0, stream>>>(zx, halo, conv_w, conv_b);
  // 3. dt softplus + per-chunk cumsum
  dtacum_kernel<<<1024, 256, 0, stream>>>(dtraw, dt_bias, A_log, dtb, acu);
  // 4. shared C·B^T and C^T
  cbt_kernel<<<256, 256, 0, stream>>>(zx, cbtb);
  ctrans_kernel<<<1024, 256, 0, stream>>>(zx, cct);
  // 5. chunk states (MFMA) + inter-chunk scan
  states_mfma<<<1024, 256, 0, stream>>>(zx, dtb, acu, st);
  chunkscan_kernel<<<2048, 256, 0, stream>>>(acu, st);
  // 6. Y (MFMA)
  ydiag_mfma<<<1024, 256, 0, stream>>>(zx, dtb, acu, cbtb, cct, st, Dp, yb);
  // 7. W_out cast
  cast_bf16_kernel<<<4096, 256, 0, stream>>>(W_out, wout16, 1048576);
  // 8. gate + RMSNorm -> bf16
  gatenorm_kernel<<<4096, 256, 0, stream>>>(zx, norm_w, yb, ybh);
  // 9. out_proj (bf16 MFMA)
  gemm_bf16<<<dim3(16, 32), 256, 0, stream>>>(ybh, 16768, wout16, 4096, out,
                                              2048, 4096, 2048);
}

// Round 4
// 697.934 us; speedup vs baseline: 5.0825x; 1.1245x over previous
//
#include <hip/hip_runtime.h>
#include <hip/hip_bf16.h>
#include <cstdint>

// Problem constants
#define DPROJ  8384

typedef __attribute__((ext_vector_type(8))) short short8;
typedef __attribute__((ext_vector_type(4))) short sh4;
typedef __attribute__((ext_vector_type(4))) float f32x4;

// workspace offsets (float units)
#define ZX_OFF     0ul
#define DTB_OFF    34340864ul   // [b][h][l] dt (softplus'd)
#define ACU_OFF    34603008ul   // [b][h][l] within-chunk cumsum of dt*A
#define CBT_OFF    34865152ul   // [b][c][s][l]  (C·B^T)^T
#define CCT_OFF    35913728ul   // [b][c][n][l]  C transposed
#define ST_OFF     36175872ul   // [b][c][h][p][n] states -> prev_states
#define YB_OFF     40370176ul   // [b][h][l][p] ssd output
#define HALO_OFF   57147392ul   // [b][lc][3][ch] conv halo
// aliases (disjoint lifetimes):
#define U16_OFF    40370176ul   // bf16 u  (dead before ydiag writes yb)
#define WIN16_OFF  48758784ul   // bf16 W_in (dead before halo written)
#define WOUT16_OFF 34340864ul   // bf16 W_out (written after ydiag frees dtb)
#define DTRAW_OFF  36175872ul   // fp32 dt raw [tok][64] (dead before states)

__device__ __forceinline__ short f2bf(float x) {
  union { float f; uint32_t u; } v{x};
  uint32_t r = (v.u + 0x7fff + ((v.u >> 16) & 1)) >> 16;
  return (short)r;
}
__device__ __forceinline__ float bf2f(short s) {
  union { uint32_t u; float f; } v;
  v.u = ((uint32_t)(uint16_t)s) << 16;
  return v.f;
}

// ---------------- fp32 -> bf16 cast (8 elems/thread) -------------------------
__global__ __launch_bounds__(256) void cast_bf16_kernel(
    const float* __restrict__ in, short* __restrict__ out, int n8) {
  int i = blockIdx.x * 256 + threadIdx.x;
  if (i >= n8) return;
  const float4* p = (const float4*)(in + (size_t)i * 8);
  float4 a = p[0], b = p[1];
  short8 o;
  o[0] = f2bf(a.x); o[1] = f2bf(a.y); o[2] = f2bf(a.z); o[3] = f2bf(a.w);
  o[4] = f2bf(b.x); o[5] = f2bf(b.y); o[6] = f2bf(b.z); o[7] = f2bf(b.w);
  *(short8*)(out + (size_t)i * 8) = o;
}

// ---------------- bf16 MFMA GEMM (NT): C[M][N] = A[M][K] * B[N][K]^T ---------
__device__ __forceinline__ void gload16(const void* g, const void* l) {
  __builtin_amdgcn_global_load_lds(
      (const __attribute__((address_space(1))) void*)g,
      (__attribute__((address_space(3))) void*)l, 16, 0, 0);
}

// XCD-chunked bijective block swizzle (nwg % 8 == 0 for all our grids):
// each XCD owns a contiguous range of tiles (4 M-rows) -> A panel resident in
// its private L2, B panel L3-resident.
__global__ __launch_bounds__(256) void gemm_bf16(
    const short* __restrict__ A, int lda, const short* __restrict__ B, int ldb,
    float* __restrict__ C, int ldc, int K, int Nvalid) {
  const int nwg = gridDim.x * gridDim.y;
  const int orig = blockIdx.x + gridDim.x * blockIdx.y;
  const int q = nwg >> 3;
  const int tile = (orig & 7) * q + (orig >> 3);
  const int tn = tile % gridDim.x;
  const int tm = tile / gridDim.x;
  __shared__ __align__(16) short As[128 * 32];
  __shared__ __align__(16) short Bs[128 * 32];
  const int t = threadIdx.x;
  const int w = t >> 6, lane = t & 63;
  const int m0 = tm * 128, n0 = tn * 128;
  const int wr = (w >> 1) * 64, wc = (w & 1) * 64;
  const int arow = t >> 2, kk = (t & 3) * 8;
  const int fr = lane & 15, fk = (lane >> 4) * 8;
  int br0 = n0 + arow;       if (br0 > Nvalid - 1) br0 = Nvalid - 1;
  int br1 = n0 + 64 + arow;  if (br1 > Nvalid - 1) br1 = Nvalid - 1;
  const short* pa0 = A + (size_t)(m0 + arow) * lda + kk;
  const short* pa1 = A + (size_t)(m0 + 64 + arow) * lda + kk;
  const short* pb0 = B + (size_t)br0 * ldb + kk;
  const short* pb1 = B + (size_t)br1 * ldb + kk;
  short* la = As + w * 512;
  short* lb = Bs + w * 512;
  f32x4 acc[4][4];
#pragma unroll
  for (int i = 0; i < 4; ++i)
#pragma unroll
    for (int j = 0; j < 4; ++j) acc[i][j] = (f32x4){0.f, 0.f, 0.f, 0.f};

  for (int k0 = 0; k0 < K; k0 += 32) {
    gload16(pa0 + k0, la);
    gload16(pa1 + k0, la + 2048);
    gload16(pb0 + k0, lb);
    gload16(pb1 + k0, lb + 2048);
    __syncthreads();
    short8 af[4], bg[4];
#pragma unroll
    for (int i = 0; i < 4; ++i) {
      af[i] = *(const short8*)&As[(wr + i * 16 + fr) * 32 + fk];
      bg[i] = *(const short8*)&Bs[(wc + i * 16 + fr) * 32 + fk];
    }
#pragma unroll
    for (int i = 0; i < 4; ++i)
#pragma unroll
      for (int j = 0; j < 4; ++j)
        acc[i][j] = __builtin_amdgcn_mfma_f32_16x16x32_bf16(af[i], bg[j],
                                                            acc[i][j], 0, 0, 0);
    __syncthreads();
  }
#pragma unroll
  for (int i = 0; i < 4; ++i) {
    const int row = m0 + wr + i * 16 + (lane >> 4) * 4;
#pragma unroll
    for (int j = 0; j < 4; ++j) {
      const int col = n0 + wc + j * 16 + fr;
      if (col < Nvalid) {
#pragma unroll
        for (int r = 0; r < 4; ++r)
          C[(size_t)(row + r) * ldc + col] = acc[i][j][r];
      }
    }
  }
}

// ---------------- small fp32 GEMM (NT) for dt columns ------------------------
__global__ __launch_bounds__(256) void gemm_f32_nt(const float* __restrict__ A,
                                                   const float* __restrict__ Bw,
                                                   float* __restrict__ C, int K,
                                                   int ldc) {
  __shared__ __align__(16) float As[16][128];
  __shared__ __align__(16) float Bs[16][64];
  const int tid = threadIdx.x;
  const int m0 = blockIdx.y * 128, n0 = blockIdx.x * 64;
  const int tm = tid & 15, tn = tid >> 4;
  const int am = tid >> 1;
  const int akq = (tid & 1) * 8;
  const int bn = tid >> 2;
  const int bk = (tid & 3) * 4;
  float acc[8][4];
#pragma unroll
  for (int i = 0; i < 8; ++i)
#pragma unroll
    for (int j = 0; j < 4; ++j) acc[i][j] = 0.f;

  for (int k0 = 0; k0 < K; k0 += 16) {
    const float* ap = A + (size_t)(m0 + am) * K + k0 + akq;
    float4 a0 = *(const float4*)ap;
    float4 a1 = *(const float4*)(ap + 4);
    float4 b0 = *(const float4*)(Bw + (size_t)(n0 + bn) * K + k0 + bk);
    __syncthreads();
    As[akq + 0][am] = a0.x; As[akq + 1][am] = a0.y;
    As[akq + 2][am] = a0.z; As[akq + 3][am] = a0.w;
    As[akq + 4][am] = a1.x; As[akq + 5][am] = a1.y;
    As[akq + 6][am] = a1.z; As[akq + 7][am] = a1.w;
    Bs[bk + 0][bn] = b0.x; Bs[bk + 1][bn] = b0.y;
    Bs[bk + 2][bn] = b0.z; Bs[bk + 3][bn] = b0.w;
    __syncthreads();
#pragma unroll
    for (int kk = 0; kk < 16; ++kk) {
      float4 x0 = *(const float4*)&As[kk][tm * 8];
      float4 x1 = *(const float4*)&As[kk][tm * 8 + 4];
      float4 y0 = *(const float4*)&Bs[kk][tn * 4];
      float av[8] = {x0.x, x0.y, x0.z, x0.w, x1.x, x1.y, x1.z, x1.w};
      float bv[4] = {y0.x, y0.y, y0.z, y0.w};
#pragma unroll
      for (int i = 0; i < 8; ++i)
#pragma unroll
        for (int j = 0; j < 4; ++j) acc[i][j] += av[i] * bv[j];
    }
  }
#pragma unroll
  for (int i = 0; i < 8; ++i) {
    float4 o = make_float4(acc[i][0], acc[i][1], acc[i][2], acc[i][3]);
    *(float4*)&C[(size_t)(m0 + tm * 8 + i) * ldc + n0 + tn * 4] = o;
  }
}

// ---------------- conv halo save (before in-place conv) ----------------------
__global__ __launch_bounds__(256) void halo_kernel(const float* __restrict__ zx,
                                                   float* __restrict__ halo) {
  int idx = blockIdx.x * 256 + threadIdx.x;
  int ch = idx % 4224;
  int r = idx / 4224;
  int j = r % 3;
  int r2 = r / 3;
  int lc = r2 & 15, b = r2 >> 4;
  int l = lc * 128 - 3 + j;
  halo[idx] = (l < 0) ? 0.f : zx[(size_t)(b * 2048 + l) * DPROJ + 4096 + ch];
}

// ---------------- causal conv1d(4) + silu, in place on xBC slice -------------
__global__ __launch_bounds__(256) void conv_kernel(float* __restrict__ zx,
                                                   const float* __restrict__ halo,
                                                   const float* __restrict__ cw,
                                                   const float* __restrict__ cb) {
  int idx = blockIdx.x * 256 + threadIdx.x;
  int ch = idx % 4224;
  int r = idx / 4224;
  int lc = r & 15, b = r >> 4;
  float w0 = cw[ch * 4 + 0], w1 = cw[ch * 4 + 1], w2 = cw[ch * 4 + 2],
        w3 = cw[ch * 4 + 3];
  float bias = cb[ch];
  const float* hp = halo + (size_t)r * 3 * 4224 + ch;
  float x3 = hp[0], x2 = hp[4224], x1 = hp[2 * 4224];
  size_t base = (size_t)(b * 2048 + lc * 128) * DPROJ + 4096 + ch;
  for (int i = 0; i < 128; ++i) {
    float x0 = zx[base];
    float v = bias + w0 * x3 + w1 * x2 + w2 * x1 + w3 * x0;
    v = v / (1.f + __expf(-v));
    zx[base] = v;
    x3 = x2; x2 = x1; x1 = x0;
    base += DPROJ;
  }
}

// ---------------- dt softplus + per-chunk cumsum of dt*A ---------------------
__global__ __launch_bounds__(256) void dtacum_kernel(
    const float* __restrict__ dtraw, const float* __restrict__ dt_bias,
    const float* __restrict__ A_log, float* __restrict__ dtb,
    float* __restrict__ acu) {
  int bid = blockIdx.x;
  int c = bid & 7, h = (bid >> 3) & 63, b = bid >> 9;
  int s = threadIdx.x;
  int tok = b * 2048 + c * 256 + s;
  float raw = dtraw[(size_t)tok * 64 + h] + dt_bias[h];
  float dtv = (raw > 20.f) ? raw : log1pf(expf(raw));
  float A = -expf(A_log[h]);
  __shared__ float sc[256];
  sc[s] = dtv * A;
  __syncthreads();
  for (int off = 1; off < 256; off <<= 1) {
    float v = (s >= off) ? sc[s - off] : 0.f;
    __syncthreads();
    sc[s] += v;
    __syncthreads();
  }
  int o = (b * 64 + h) * 2048 + c * 256 + s;
  dtb[o] = dtv;
  acu[o] = sc[s];
}

// ---------------- CB^T per (b,c): cbt[s][l] = sum_n C[l,n]*B[s,n] ------------
__global__ __launch_bounds__(256) void cbt_kernel(const float* __restrict__ zx,
                                                  float* __restrict__ cbt) {
  __shared__ float cl[256][33];
  __shared__ float blds[16][32];
  int bid = blockIdx.x;
  int sb = bid & 15, c = (bid >> 4) & 7, b = bid >> 7;
  int t = threadIdx.x;
  int tok0 = b * 2048 + c * 256;
  float acc[16];
#pragma unroll
  for (int i = 0; i < 16; ++i) acc[i] = 0.f;
  for (int nh = 0; nh < 2; ++nh) {
    __syncthreads();
    for (int it = 0; it < 32; ++it) {
      int e = it * 256 + t;
      int row = e >> 5, n = e & 31;
      cl[row][n] = zx[(size_t)(tok0 + row) * DPROJ + 8256 + nh * 32 + n];
    }
    for (int it = 0; it < 2; ++it) {
      int e = it * 256 + t;
      int row = e >> 5, n = e & 31;
      blds[row][n] =
          zx[(size_t)(tok0 + sb * 16 + row) * DPROJ + 8192 + nh * 32 + n];
    }
    __syncthreads();
    for (int n = 0; n < 32; ++n) {
      float cv = cl[t][n];
#pragma unroll
      for (int s2 = 0; s2 < 16; ++s2) acc[s2] += cv * blds[s2][n];
    }
  }
#pragma unroll
  for (int s2 = 0; s2 < 16; ++s2)
    cbt[((size_t)(b * 8 + c) * 256 + sb * 16 + s2) * 256 + t] = acc[s2];
}

// ---------------- C transpose: cct[b][c][n][l] -------------------------------
__global__ __launch_bounds__(256) void ctrans_kernel(const float* __restrict__ zx,
                                                     float* __restrict__ cct) {
  int idx = blockIdx.x * 256 + threadIdx.x;
  int l = idx & 255, n = (idx >> 8) & 63, bc = idx >> 14;
  int b = bc >> 3, c = bc & 7;
  cct[idx] = zx[(size_t)(b * 2048 + c * 256 + l) * DPROJ + 8256 + n];
}

// ---------------- states (MFMA): st[p][n] = sum_s x[s,p] B[s,n] w[s] ---------
__global__ __launch_bounds__(256) void states_mfma(
    const float* __restrict__ zx, const float* __restrict__ dtb,
    const float* __restrict__ acu, float* __restrict__ st) {
  __shared__ __align__(16) short As2[64][136];  // X^T [p][k]
  __shared__ __align__(16) short Bs2[64][136];  // (B·w)^T [n][k]
  __shared__ float wl[256];
  int bid = blockIdx.x;  // (b*8+c)*64 + h
  int h = bid & 63, c = (bid >> 6) & 7, b = bid >> 9;
  int t = threadIdx.x;
  int w = t >> 6, lane = t & 63;
  int tok0 = b * 2048 + c * 256;
  int bh = (b * 64 + h) * 2048 + c * 256;
  {
    float aend = acu[bh + 255];
    wl[t] = __expf(aend - acu[bh + t]) * dtb[bh + t];
  }
  __syncthreads();
  const float* xbase = zx + (size_t)tok0 * DPROJ + 4096 + h * 64;
  const float* bbase = zx + (size_t)tok0 * DPROJ + 8192;
  const int fr = lane & 15, fko = (lane >> 4) * 8;
  const int wi = (w >> 1) * 32, wj = (w & 1) * 32;
  f32x4 acc[2][2];
#pragma unroll
  for (int i = 0; i < 2; ++i)
#pragma unroll
    for (int j = 0; j < 2; ++j) acc[i][j] = (f32x4){0.f, 0.f, 0.f, 0.f};

  for (int ph = 0; ph < 2; ++ph) {
    const int kb = ph * 128;
    if (ph) __syncthreads();
    for (int it = 0; it < 8; ++it) {
      int idx = it * 256 + t;
      int p = idx & 63, kg = idx >> 6;  // kg 0..31
      int k = kb + kg * 4;
      const float* xp = xbase + (size_t)k * DPROJ + p;
      const float* bp = bbase + (size_t)k * DPROJ + p;
      sh4 oa, ob;
#pragma unroll
      for (int r = 0; r < 4; ++r) {
        oa[r] = f2bf(xp[(size_t)r * DPROJ]);
        ob[r] = f2bf(bp[(size_t)r * DPROJ] * wl[k + r]);
      }
      *(sh4*)&As2[p][kg * 4] = oa;
      *(sh4*)&Bs2[p][kg * 4] = ob;
    }
    __syncthreads();
#pragma unroll
    for (int kk0 = 0; kk0 < 128; kk0 += 32) {
      short8 af[2], bg[2];
#pragma unroll
      for (int i = 0; i < 2; ++i) {
        af[i] = *(const short8*)&As2[wi + i * 16 + fr][kk0 + fko];
        bg[i] = *(const short8*)&Bs2[wj + i * 16 + fr][kk0 + fko];
      }
#pragma unroll
      for (int i = 0; i < 2; ++i)
#pragma unroll
        for (int j = 0; j < 2; ++j)
          acc[i][j] = __builtin_amdgcn_mfma_f32_16x16x32_bf16(af[i], bg[j],
                                                              acc[i][j], 0, 0, 0);
    }
  }
  float* out = st + ((size_t)(b * 8 + c) * 64 + h) * 4096;
  const int rq = (lane >> 4) * 4;
#pragma unroll
  for (int i = 0; i < 2; ++i) {
    int p0 = wi + i * 16 + rq;
#pragma unroll
    for (int j = 0; j < 2; ++j) {
      int n = wj + j * 16 + fr;
#pragma unroll
      for (int r = 0; r < 4; ++r)
        out[(size_t)(p0 + r) * 64 + n] = acc[i][j][r];
    }
  }
}

// ---------------- inter-chunk scan (in place states -> prev_states) ---------
__global__ __launch_bounds__(256) void chunkscan_kernel(
    const float* __restrict__ acu, float* __restrict__ st) {
  int bid = blockIdx.x;
  int pc = bid & 15, h = (bid >> 4) & 63, b = bid >> 10;
  int pn = pc * 256 + threadIdx.x;
  int abase = (b * 64 + h) * 2048;
  float run = 0.f;
  for (int c = 0; c < 8; ++c) {
    size_t idx = ((size_t)(b * 8 + c) * 64 + h) * 4096 + pn;
    float s = st[idx];
    st[idx] = run;
    float ach = acu[abase + c * 256 + 255];
    run = run * __expf(ach) + s;
  }
}

// ---------------- Y (MFMA): M=256 l, N=64 p, K=320 (256 s + 64 n) ------------
// Decay A-fragments built via per-k-step rank-1 rebasing:
//   exp(Al - acs[s]) = exp(Al - base) * exp(base - acs[s]), base = acs[k0+32]
// valid (both factors <= 1) for fragments strictly below the diagonal.
__global__ __launch_bounds__(256) void ydiag_mfma(
    const float* __restrict__ zx, const float* __restrict__ dtb,
    const float* __restrict__ acu, const float* __restrict__ cbt,
    const float* __restrict__ cct, const float* __restrict__ st,
    const float* __restrict__ Dp, float* __restrict__ yb) {
  __shared__ __align__(16) short Xs[64][328];  // [p][k]: k<256 x, k>=256 prev
  __shared__ float acs[256];
  __shared__ float dts[256];
  int bid = blockIdx.x;  // (b*8+c)*64 + h
  int h = bid & 63, c = (bid >> 6) & 7, b = bid >> 9;
  int t = threadIdx.x;
  int w = t >> 6, lane = t & 63;
  int tok0 = b * 2048 + c * 256;
  int bh = (b * 64 + h) * 2048 + c * 256;
  acs[t] = acu[bh + t];
  dts[t] = dtb[bh + t];
  const float* xbase = zx + (size_t)tok0 * DPROJ + 4096 + h * 64;
  const float* st_b = st + ((size_t)(b * 8 + c) * 64 + h) * 4096;
  // stage x^T (bf16): Xs[p][k] = x[tok0+k][p]
  for (int it = 0; it < 16; ++it) {
    int idx = it * 256 + t;
    int p = idx & 63, kg = idx >> 6;  // kg 0..63
    const float* xp = xbase + (size_t)(kg * 4) * DPROJ + p;
    sh4 o;
    o[0] = f2bf(xp[0]);
    o[1] = f2bf(xp[DPROJ]);
    o[2] = f2bf(xp[2 * DPROJ]);
    o[3] = f2bf(xp[3 * DPROJ]);
    *(sh4*)&Xs[p][kg * 4] = o;
  }
  // stage prev^T: Xs[p][256+n] = prev[n][p] = st[p][n]
  for (int it = 0; it < 4; ++it) {
    int idx = it * 256 + t;
    int ng = idx & 15, p = idx >> 4;
    float4 v = *(const float4*)&st_b[p * 64 + ng * 4];
    sh4 o;
    o[0] = f2bf(v.x); o[1] = f2bf(v.y); o[2] = f2bf(v.z); o[3] = f2bf(v.w);
    *(sh4*)&Xs[p][256 + ng * 4] = o;
  }
  __syncthreads();

  const int fr = lane & 15, fko = (lane >> 4) * 8;
  const int wr = w * 64;
  float Al[4], eAl[4];
#pragma unroll
  for (int i = 0; i < 4; ++i) {
    Al[i] = acs[wr + i * 16 + fr];
    eAl[i] = __expf(Al[i]);
  }
  f32x4 acc[4][4];
#pragma unroll
  for (int i = 0; i < 4; ++i)
#pragma unroll
    for (int j = 0; j < 4; ++j) acc[i][j] = (f32x4){0.f, 0.f, 0.f, 0.f};

  const float* cbt_b = cbt + (size_t)(b * 8 + c) * 65536;
  const float* cct_b = cct + (size_t)(b * 8 + c) * 16384;

  // masked decay part: s in [0, wr+64)
  for (int k0 = 0; k0 < wr + 64; k0 += 32) {
    short8 bg[4];
#pragma unroll
    for (int j = 0; j < 4; ++j)
      bg[j] = *(const short8*)&Xs[j * 16 + fr][k0 + fko];
    const int bi = (k0 + 32 < 256) ? (k0 + 32) : 255;
    const float base = acs[bi];
    float vd[8];
#pragma unroll
    for (int jj = 0; jj < 8; ++jj) {
      int s = k0 + fko + jj;
      vd[jj] = __expf(base - acs[s]) * dts[s];
    }
#pragma unroll
    for (int i = 0; i < 4; ++i) {
      const int li0 = wr + i * 16;
      if (k0 > li0 + 15) continue;  // fragment fully above diagonal: zero
      const int l = li0 + fr;
      short8 af;
      if (k0 + 32 <= li0) {
        // fast path: strictly below diagonal, rank-1 rebased
        const float u = __expf(Al[i] - base);
#pragma unroll
        for (int jj = 0; jj < 8; ++jj) {
          int s = k0 + fko + jj;
          af[jj] = f2bf(cbt_b[s * 256 + l] * vd[jj] * u);
        }
      } else {
        // crossing fragment: exact masked exp
#pragma unroll
        for (int jj = 0; jj < 8; ++jj) {
          int s = k0 + fko + jj;
          float wv = 0.f;
          if (s <= l) wv = cbt_b[s * 256 + l] * __expf(Al[i] - acs[s]) * dts[s];
          af[jj] = f2bf(wv);
        }
      }
#pragma unroll
      for (int j = 0; j < 4; ++j)
        acc[i][j] = __builtin_amdgcn_mfma_f32_16x16x32_bf16(af, bg[j],
                                                            acc[i][j], 0, 0, 0);
    }
  }
  // Y_off part: k in [256, 320) -> n = k-256
#pragma unroll
  for (int k0 = 256; k0 < 320; k0 += 32) {
    short8 bg[4];
#pragma unroll
    for (int j = 0; j < 4; ++j)
      bg[j] = *(const short8*)&Xs[j * 16 + fr][k0 + fko];
#pragma unroll
    for (int i = 0; i < 4; ++i) {
      const int l = wr + i * 16 + fr;
      short8 af;
#pragma unroll
      for (int jj = 0; jj < 8; ++jj) {
        int n = k0 - 256 + fko + jj;
        af[jj] = f2bf(cct_b[n * 256 + l] * eAl[i]);
      }
#pragma unroll
      for (int j = 0; j < 4; ++j)
        acc[i][j] = __builtin_amdgcn_mfma_f32_16x16x32_bf16(af, bg[j],
                                                            acc[i][j], 0, 0, 0);
    }
  }
  // epilogue: + D*x, store
  float Dh = Dp[h];
  const int rq = (lane >> 4) * 4;
#pragma unroll
  for (int i = 0; i < 4; ++i) {
    int l0 = wr + i * 16 + rq;
#pragma unroll
    for (int j = 0; j < 4; ++j) {
      int p = j * 16 + fr;
      sh4 x4 = *(const sh4*)&Xs[p][l0];
      f32x4 a = acc[i][j];
#pragma unroll
      for (int r = 0; r < 4; ++r)
        yb[(size_t)(bh + l0 + r) * 64 + p] = a[r] + Dh * bf2f(x4[r]);
    }
  }
}

// ---------------- gate + RMSNorm -> bf16 activations (aliases zx z-slice) ----
__global__ __launch_bounds__(256) void gatenorm_kernel(
    const float* zx, const float* __restrict__ nw,
    const float* __restrict__ yb, short* ybh) {
  int tok = blockIdx.x;
  int b = tok >> 11, l = tok & 2047;
  int t = threadIdx.x;
  float g[16];
  float ss = 0.f;
#pragma unroll
  for (int i = 0; i < 16; ++i) {
    int d = i * 256 + t;
    int h = d >> 6, p = d & 63;
    float yv = yb[((size_t)(b * 64 + h) * 2048 + l) * 64 + p];
    float zv = zx[(size_t)tok * DPROJ + d];
    float gv = yv * (zv / (1.f + __expf(-zv)));
    g[i] = gv;
    ss += gv * gv;
  }
  for (int off = 32; off > 0; off >>= 1) ss += __shfl_down(ss, off);
  __shared__ float red[4];
  int wid = t >> 6, lane = t & 63;
  if (lane == 0) red[wid] = ss;
  __syncthreads();
  float tot = red[0] + red[1] + red[2] + red[3];
  float scale = rsqrtf(tot * (1.f / 4096.f) + 1e-5f);
#pragma unroll
  for (int i = 0; i < 16; ++i) {
    int d = i * 256 + t;
    ybh[(size_t)tok * 16768 + d] = f2bf(g[i] * scale * nw[d]);
  }
}

extern "C" void kernel_launch(void* const* d_in, const int* in_sizes, int n_in,
                              void* d_out, int out_size, void* d_ws,
                              size_t ws_size, hipStream_t stream) {
  const float* u = (const float*)d_in[0];
  const float* W_in = (const float*)d_in[1];
  const float* conv_w = (const float*)d_in[2];
  const float* conv_b = (const float*)d_in[3];
  const float* dt_bias = (const float*)d_in[4];
  const float* A_log = (const float*)d_in[5];
  const float* Dp = (const float*)d_in[6];
  const float* norm_w = (const float*)d_in[7];
  const float* W_out = (const float*)d_in[8];
  float* out = (float*)d_out;
  float* ws = (float*)d_ws;

  float* zx = ws + ZX_OFF;
  float* dtb = ws + DTB_OFF;
  float* acu = ws + ACU_OFF;
  float* cbtb = ws + CBT_OFF;
  float* cct = ws + CCT_OFF;
  float* st = ws + ST_OFF;
  float* yb = ws + YB_OFF;
  float* halo = ws + HALO_OFF;
  float* dtraw = ws + DTRAW_OFF;
  short* u16 = (short*)(ws + U16_OFF);
  short* win16 = (short*)(ws + WIN16_OFF);
  short* wout16 = (short*)(ws + WOUT16_OFF);
  short* ybh = (short*)zx;

  // 0. casts for in_proj
  cast_bf16_kernel<<<4096, 256, 0, stream>>>(u, u16, 1048576);
  cast_bf16_kernel<<<8384, 256, 0, stream>>>(W_in, win16, 2146304);
  // 1. in_proj (bf16 MFMA): zx = u @ W_in^T
  gemm_bf16<<<dim3(66, 32), 256, 0, stream>>>(u16, 2048, win16, 2048, zx, DPROJ,
                                              2048, DPROJ);
  // 1b. dt columns in fp32 (exp-sensitive)
  gemm_f32_nt<<<dim3(1, 32), 256, 0, stream>>>(u, W_in + 8320ul * 2048, dtraw,
                                               2048, 64);
  // 2. conv halo, in-place conv+silu
  halo_kernel<<<1584, 256, 0, stream>>>(zx, halo);
  conv_kernel<<<528, 256, 0, stream>>>(zx, halo, conv_w, conv_b);
  // 3. dt softplus + per-chunk cumsum
  dtacum_kernel<<<1024, 256, 0, stream>>>(dtraw, dt_bias, A_log, dtb, acu);
  // 4. shared C·B^T and C^T
  cbt_kernel<<<256, 256, 0, stream>>>(zx, cbtb);
  ctrans_kernel<<<1024, 256, 0, stream>>>(zx, cct);
  // 5. chunk states (MFMA) + inter-chunk scan
  states_mfma<<<1024, 256, 0, stream>>>(zx, dtb, acu, st);
  chunkscan_kernel<<<2048, 256, 0, stream>>>(acu, st);
  // 6. Y (MFMA)
  ydiag_mfma<<<1024, 256, 0, stream>>>(zx, dtb, acu, cbtb, cct, st, Dp, yb);
  // 7. W_out cast
  cast_bf16_kernel<<<4096, 256, 0, stream>>>(W_out, wout16, 1048576);
  // 8. gate + RMSNorm -> bf16
  gatenorm_kernel<<<4096, 256, 0, stream>>>(zx, norm_w, yb, ybh);
  // 9. out_proj (bf16 MFMA)
  gemm_bf16<<<dim3(16, 32), 256, 0, stream>>>(ybh, 16768, wout16, 4096, out,
                                              2048, 4096, 2048);
}

// Round 5
// 690.818 us; speedup vs baseline: 5.1348x; 1.0103x over previous
//
#include <hip/hip_runtime.h>
#include <hip/hip_bf16.h>
#include <cstdint>

// Problem constants
#define DPROJ  8384

typedef __attribute__((ext_vector_type(8))) short short8;
typedef __attribute__((ext_vector_type(4))) short sh4;
typedef __attribute__((ext_vector_type(4))) float f32x4;

// workspace offsets (float units)
#define ZX_OFF     0ul
#define DTB_OFF    34340864ul   // [b][h][l] dt (softplus'd)
#define ACU_OFF    34603008ul   // [b][h][l] within-chunk cumsum of dt*A
#define CBT_OFF    34865152ul   // [b][c][s][l]  (C·B^T)^T
#define CCT_OFF    35913728ul   // [b][c][n][l]  C transposed
#define ST_OFF     36175872ul   // [b][c][h][p][n] states -> prev_states
#define YB_OFF     40370176ul   // [b][h][l][p] ssd output
#define HALO_OFF   57147392ul   // [b][lc][3][ch] conv halo
// aliases (disjoint lifetimes):
#define U16_OFF    40370176ul   // bf16 u  (dead before ydiag writes yb)
#define WIN16_OFF  48758784ul   // bf16 W_in (dead before halo written)
#define WOUT16_OFF 34340864ul   // bf16 W_out (written after ydiag frees dtb)
#define DTRAW_OFF  36175872ul   // fp32 dt raw [tok][64] (dead before states)

__device__ __forceinline__ short f2bf(float x) {
  union { float f; uint32_t u; } v{x};
  uint32_t r = (v.u + 0x7fff + ((v.u >> 16) & 1)) >> 16;
  return (short)r;
}
__device__ __forceinline__ float bf2f(short s) {
  union { uint32_t u; float f; } v;
  v.u = ((uint32_t)(uint16_t)s) << 16;
  return v.f;
}

// ---------------- fp32 -> bf16 cast (8 elems/thread) -------------------------
__global__ __launch_bounds__(256) void cast_bf16_kernel(
    const float* __restrict__ in, short* __restrict__ out, int n8) {
  int i = blockIdx.x * 256 + threadIdx.x;
  if (i >= n8) return;
  const float4* p = (const float4*)(in + (size_t)i * 8);
  float4 a = p[0], b = p[1];
  short8 o;
  o[0] = f2bf(a.x); o[1] = f2bf(a.y); o[2] = f2bf(a.z); o[3] = f2bf(a.w);
  o[4] = f2bf(b.x); o[5] = f2bf(b.y); o[6] = f2bf(b.z); o[7] = f2bf(b.w);
  *(short8*)(out + (size_t)i * 8) = o;
}

// ---------------- bf16 MFMA GEMM (NT): C[M][N] = A[M][K] * B[N][K]^T ---------
__device__ __forceinline__ void gload16(const void* g, const void* l) {
  __builtin_amdgcn_global_load_lds(
      (const __attribute__((address_space(1))) void*)g,
      (__attribute__((address_space(3))) void*)l, 16, 0, 0);
}

// XCD-chunked swizzle, m-fastest within chunk: each XCD owns 4 contiguous
// M-rows; consecutive blocks on one XCD share the B-tile (reuse distance
// 0.5 MB) and cycle 4 A-tiles (2 MB) -> both panels L2-resident per XCD.
// Requires gridDim.y % 8 == 0 (32 for both our GEMMs).
__global__ __launch_bounds__(256) void gemm_bf16(
    const short* __restrict__ A, int lda, const short* __restrict__ B, int ldb,
    float* __restrict__ C, int ldc, int K, int Nvalid) {
  const int orig = blockIdx.x + gridDim.x * blockIdx.y;
  const int xcd = orig & 7;
  const int cid = orig >> 3;
  const int rpx = gridDim.y >> 3;  // rows per XCD (4)
  const int tn = cid / rpx;
  const int tm = xcd * rpx + (cid % rpx);
  __shared__ __align__(16) short As[128 * 32];
  __shared__ __align__(16) short Bs[128 * 32];
  const int t = threadIdx.x;
  const int w = t >> 6, lane = t & 63;
  const int m0 = tm * 128, n0 = tn * 128;
  const int wr = (w >> 1) * 64, wc = (w & 1) * 64;
  const int arow = t >> 2, kk = (t & 3) * 8;
  const int fr = lane & 15, fk = (lane >> 4) * 8;
  int br0 = n0 + arow;       if (br0 > Nvalid - 1) br0 = Nvalid - 1;
  int br1 = n0 + 64 + arow;  if (br1 > Nvalid - 1) br1 = Nvalid - 1;
  const short* pa0 = A + (size_t)(m0 + arow) * lda + kk;
  const short* pa1 = A + (size_t)(m0 + 64 + arow) * lda + kk;
  const short* pb0 = B + (size_t)br0 * ldb + kk;
  const short* pb1 = B + (size_t)br1 * ldb + kk;
  short* la = As + w * 512;
  short* lb = Bs + w * 512;
  f32x4 acc[4][4];
#pragma unroll
  for (int i = 0; i < 4; ++i)
#pragma unroll
    for (int j = 0; j < 4; ++j) acc[i][j] = (f32x4){0.f, 0.f, 0.f, 0.f};

  for (int k0 = 0; k0 < K; k0 += 32) {
    gload16(pa0 + k0, la);
    gload16(pa1 + k0, la + 2048);
    gload16(pb0 + k0, lb);
    gload16(pb1 + k0, lb + 2048);
    __syncthreads();
    short8 af[4], bg[4];
#pragma unroll
    for (int i = 0; i < 4; ++i) {
      af[i] = *(const short8*)&As[(wr + i * 16 + fr) * 32 + fk];
      bg[i] = *(const short8*)&Bs[(wc + i * 16 + fr) * 32 + fk];
    }
#pragma unroll
    for (int i = 0; i < 4; ++i)
#pragma unroll
      for (int j = 0; j < 4; ++j)
        acc[i][j] = __builtin_amdgcn_mfma_f32_16x16x32_bf16(af[i], bg[j],
                                                            acc[i][j], 0, 0, 0);
    __syncthreads();
  }
#pragma unroll
  for (int i = 0; i < 4; ++i) {
    const int row = m0 + wr + i * 16 + (lane >> 4) * 4;
#pragma unroll
    for (int j = 0; j < 4; ++j) {
      const int col = n0 + wc + j * 16 + fr;
      if (col < Nvalid) {
#pragma unroll
        for (int r = 0; r < 4; ++r)
          C[(size_t)(row + r) * ldc + col] = acc[i][j][r];
      }
    }
  }
}

// ---------------- small fp32 GEMM (NT) for dt columns ------------------------
__global__ __launch_bounds__(256) void gemm_f32_nt(const float* __restrict__ A,
                                                   const float* __restrict__ Bw,
                                                   float* __restrict__ C, int K,
                                                   int ldc) {
  __shared__ __align__(16) float As[16][128];
  __shared__ __align__(16) float Bs[16][64];
  const int tid = threadIdx.x;
  const int m0 = blockIdx.y * 128, n0 = blockIdx.x * 64;
  const int tm = tid & 15, tn = tid >> 4;
  const int am = tid >> 1;
  const int akq = (tid & 1) * 8;
  const int bn = tid >> 2;
  const int bk = (tid & 3) * 4;
  float acc[8][4];
#pragma unroll
  for (int i = 0; i < 8; ++i)
#pragma unroll
    for (int j = 0; j < 4; ++j) acc[i][j] = 0.f;

  for (int k0 = 0; k0 < K; k0 += 16) {
    const float* ap = A + (size_t)(m0 + am) * K + k0 + akq;
    float4 a0 = *(const float4*)ap;
    float4 a1 = *(const float4*)(ap + 4);
    float4 b0 = *(const float4*)(Bw + (size_t)(n0 + bn) * K + k0 + bk);
    __syncthreads();
    As[akq + 0][am] = a0.x; As[akq + 1][am] = a0.y;
    As[akq + 2][am] = a0.z; As[akq + 3][am] = a0.w;
    As[akq + 4][am] = a1.x; As[akq + 5][am] = a1.y;
    As[akq + 6][am] = a1.z; As[akq + 7][am] = a1.w;
    Bs[bk + 0][bn] = b0.x; Bs[bk + 1][bn] = b0.y;
    Bs[bk + 2][bn] = b0.z; Bs[bk + 3][bn] = b0.w;
    __syncthreads();
#pragma unroll
    for (int kk = 0; kk < 16; ++kk) {
      float4 x0 = *(const float4*)&As[kk][tm * 8];
      float4 x1 = *(const float4*)&As[kk][tm * 8 + 4];
      float4 y0 = *(const float4*)&Bs[kk][tn * 4];
      float av[8] = {x0.x, x0.y, x0.z, x0.w, x1.x, x1.y, x1.z, x1.w};
      float bv[4] = {y0.x, y0.y, y0.z, y0.w};
#pragma unroll
      for (int i = 0; i < 8; ++i)
#pragma unroll
        for (int j = 0; j < 4; ++j) acc[i][j] += av[i] * bv[j];
    }
  }
#pragma unroll
  for (int i = 0; i < 8; ++i) {
    float4 o = make_float4(acc[i][0], acc[i][1], acc[i][2], acc[i][3]);
    *(float4*)&C[(size_t)(m0 + tm * 8 + i) * ldc + n0 + tn * 4] = o;
  }
}

// ---------------- conv halo save (before in-place conv) ----------------------
__global__ __launch_bounds__(256) void halo_kernel(const float* __restrict__ zx,
                                                   float* __restrict__ halo) {
  int idx = blockIdx.x * 256 + threadIdx.x;
  int ch = idx % 4224;
  int r = idx / 4224;
  int j = r % 3;
  int r2 = r / 3;
  int lc = r2 & 15, b = r2 >> 4;
  int l = lc * 128 - 3 + j;
  halo[idx] = (l < 0) ? 0.f : zx[(size_t)(b * 2048 + l) * DPROJ + 4096 + ch];
}

// ---------------- causal conv1d(4) + silu, in place on xBC slice -------------
__global__ __launch_bounds__(256) void conv_kernel(float* __restrict__ zx,
                                                   const float* __restrict__ halo,
                                                   const float* __restrict__ cw,
                                                   const float* __restrict__ cb) {
  int idx = blockIdx.x * 256 + threadIdx.x;
  int ch = idx % 4224;
  int r = idx / 4224;
  int lc = r & 15, b = r >> 4;
  float w0 = cw[ch * 4 + 0], w1 = cw[ch * 4 + 1], w2 = cw[ch * 4 + 2],
        w3 = cw[ch * 4 + 3];
  float bias = cb[ch];
  const float* hp = halo + (size_t)r * 3 * 4224 + ch;
  float x3 = hp[0], x2 = hp[4224], x1 = hp[2 * 4224];
  size_t base = (size_t)(b * 2048 + lc * 128) * DPROJ + 4096 + ch;
  for (int i = 0; i < 128; ++i) {
    float x0 = zx[base];
    float v = bias + w0 * x3 + w1 * x2 + w2 * x1 + w3 * x0;
    v = v / (1.f + __expf(-v));
    zx[base] = v;
    x3 = x2; x2 = x1; x1 = x0;
    base += DPROJ;
  }
}

// ---------------- dt softplus + per-chunk cumsum of dt*A ---------------------
__global__ __launch_bounds__(256) void dtacum_kernel(
    const float* __restrict__ dtraw, const float* __restrict__ dt_bias,
    const float* __restrict__ A_log, float* __restrict__ dtb,
    float* __restrict__ acu) {
  int bid = blockIdx.x;
  int c = bid & 7, h = (bid >> 3) & 63, b = bid >> 9;
  int s = threadIdx.x;
  int tok = b * 2048 + c * 256 + s;
  float raw = dtraw[(size_t)tok * 64 + h] + dt_bias[h];
  float dtv = (raw > 20.f) ? raw : log1pf(expf(raw));
  float A = -expf(A_log[h]);
  __shared__ float sc[256];
  sc[s] = dtv * A;
  __syncthreads();
  for (int off = 1; off < 256; off <<= 1) {
    float v = (s >= off) ? sc[s - off] : 0.f;
    __syncthreads();
    sc[s] += v;
    __syncthreads();
  }
  int o = (b * 64 + h) * 2048 + c * 256 + s;
  dtb[o] = dtv;
  acu[o] = sc[s];
}

// ---------------- CB^T per (b,c): cbt[s][l] = sum_n C[l,n]*B[s,n] ------------
__global__ __launch_bounds__(256) void cbt_kernel(const float* __restrict__ zx,
                                                  float* __restrict__ cbt) {
  __shared__ float cl[256][33];
  __shared__ float blds[16][32];
  int bid = blockIdx.x;
  int sb = bid & 15, c = (bid >> 4) & 7, b = bid >> 7;
  int t = threadIdx.x;
  int tok0 = b * 2048 + c * 256;
  float acc[16];
#pragma unroll
  for (int i = 0; i < 16; ++i) acc[i] = 0.f;
  for (int nh = 0; nh < 2; ++nh) {
    __syncthreads();
    for (int it = 0; it < 32; ++it) {
      int e = it * 256 + t;
      int row = e >> 5, n = e & 31;
      cl[row][n] = zx[(size_t)(tok0 + row) * DPROJ + 8256 + nh * 32 + n];
    }
    for (int it = 0; it < 2; ++it) {
      int e = it * 256 + t;
      int row = e >> 5, n = e & 31;
      blds[row][n] =
          zx[(size_t)(tok0 + sb * 16 + row) * DPROJ + 8192 + nh * 32 + n];
    }
    __syncthreads();
    for (int n = 0; n < 32; ++n) {
      float cv = cl[t][n];
#pragma unroll
      for (int s2 = 0; s2 < 16; ++s2) acc[s2] += cv * blds[s2][n];
    }
  }
#pragma unroll
  for (int s2 = 0; s2 < 16; ++s2)
    cbt[((size_t)(b * 8 + c) * 256 + sb * 16 + s2) * 256 + t] = acc[s2];
}

// ---------------- C transpose: cct[b][c][n][l] -------------------------------
__global__ __launch_bounds__(256) void ctrans_kernel(const float* __restrict__ zx,
                                                     float* __restrict__ cct) {
  int idx = blockIdx.x * 256 + threadIdx.x;
  int l = idx & 255, n = (idx >> 8) & 63, bc = idx >> 14;
  int b = bc >> 3, c = bc & 7;
  cct[idx] = zx[(size_t)(b * 2048 + c * 256 + l) * DPROJ + 8256 + n];
}

// ---------------- states (MFMA): st[p][n] = sum_s x[s,p] B[s,n] w[s] ---------
__global__ __launch_bounds__(256) void states_mfma(
    const float* __restrict__ zx, const float* __restrict__ dtb,
    const float* __restrict__ acu, float* __restrict__ st) {
  __shared__ __align__(16) short As2[64][136];  // X^T [p][k]
  __shared__ __align__(16) short Bs2[64][136];  // (B·w)^T [n][k]
  __shared__ float wl[256];
  int bid = blockIdx.x;  // (b*8+c)*64 + h
  int h = bid & 63, c = (bid >> 6) & 7, b = bid >> 9;
  int t = threadIdx.x;
  int w = t >> 6, lane = t & 63;
  int tok0 = b * 2048 + c * 256;
  int bh = (b * 64 + h) * 2048 + c * 256;
  {
    float aend = acu[bh + 255];
    wl[t] = __expf(aend - acu[bh + t]) * dtb[bh + t];
  }
  __syncthreads();
  const float* xbase = zx + (size_t)tok0 * DPROJ + 4096 + h * 64;
  const float* bbase = zx + (size_t)tok0 * DPROJ + 8192;
  const int fr = lane & 15, fko = (lane >> 4) * 8;
  const int wi = (w >> 1) * 32, wj = (w & 1) * 32;
  f32x4 acc[2][2];
#pragma unroll
  for (int i = 0; i < 2; ++i)
#pragma unroll
    for (int j = 0; j < 2; ++j) acc[i][j] = (f32x4){0.f, 0.f, 0.f, 0.f};

  for (int ph = 0; ph < 2; ++ph) {
    const int kb = ph * 128;
    if (ph) __syncthreads();
    for (int it = 0; it < 8; ++it) {
      int idx = it * 256 + t;
      int p = idx & 63, kg = idx >> 6;  // kg 0..31
      int k = kb + kg * 4;
      const float* xp = xbase + (size_t)k * DPROJ + p;
      const float* bp = bbase + (size_t)k * DPROJ + p;
      sh4 oa, ob;
#pragma unroll
      for (int r = 0; r < 4; ++r) {
        oa[r] = f2bf(xp[(size_t)r * DPROJ]);
        ob[r] = f2bf(bp[(size_t)r * DPROJ] * wl[k + r]);
      }
      *(sh4*)&As2[p][kg * 4] = oa;
      *(sh4*)&Bs2[p][kg * 4] = ob;
    }
    __syncthreads();
#pragma unroll
    for (int kk0 = 0; kk0 < 128; kk0 += 32) {
      short8 af[2], bg[2];
#pragma unroll
      for (int i = 0; i < 2; ++i) {
        af[i] = *(const short8*)&As2[wi + i * 16 + fr][kk0 + fko];
        bg[i] = *(const short8*)&Bs2[wj + i * 16 + fr][kk0 + fko];
      }
#pragma unroll
      for (int i = 0; i < 2; ++i)
#pragma unroll
        for (int j = 0; j < 2; ++j)
          acc[i][j] = __builtin_amdgcn_mfma_f32_16x16x32_bf16(af[i], bg[j],
                                                              acc[i][j], 0, 0, 0);
    }
  }
  float* out = st + ((size_t)(b * 8 + c) * 64 + h) * 4096;
  const int rq = (lane >> 4) * 4;
#pragma unroll
  for (int i = 0; i < 2; ++i) {
    int p0 = wi + i * 16 + rq;
#pragma unroll
    for (int j = 0; j < 2; ++j) {
      int n = wj + j * 16 + fr;
#pragma unroll
      for (int r = 0; r < 4; ++r)
        out[(size_t)(p0 + r) * 64 + n] = acc[i][j][r];
    }
  }
}

// ---------------- inter-chunk scan (in place states -> prev_states) ---------
__global__ __launch_bounds__(256) void chunkscan_kernel(
    const float* __restrict__ acu, float* __restrict__ st) {
  int bid = blockIdx.x;
  int pc = bid & 15, h = (bid >> 4) & 63, b = bid >> 10;
  int pn = pc * 256 + threadIdx.x;
  int abase = (b * 64 + h) * 2048;
  float run = 0.f;
  for (int c = 0; c < 8; ++c) {
    size_t idx = ((size_t)(b * 8 + c) * 64 + h) * 4096 + pn;
    float s = st[idx];
    st[idx] = run;
    float ach = acu[abase + c * 256 + 255];
    run = run * __expf(ach) + s;
  }
}

// ---------------- Y (MFMA): M=256 l, N=64 p, K=320 (256 s + 64 n) ------------
__global__ __launch_bounds__(256) void ydiag_mfma(
    const float* __restrict__ zx, const float* __restrict__ dtb,
    const float* __restrict__ acu, const float* __restrict__ cbt,
    const float* __restrict__ cct, const float* __restrict__ st,
    const float* __restrict__ Dp, float* __restrict__ yb) {
  __shared__ __align__(16) short Xs[64][328];  // [p][k]: k<256 x, k>=256 prev
  __shared__ float acs[256];
  __shared__ float dts[256];
  int bid = blockIdx.x;  // (b*8+c)*64 + h
  int h = bid & 63, c = (bid >> 6) & 7, b = bid >> 9;
  int t = threadIdx.x;
  int w = t >> 6, lane = t & 63;
  int tok0 = b * 2048 + c * 256;
  int bh = (b * 64 + h) * 2048 + c * 256;
  acs[t] = acu[bh + t];
  dts[t] = dtb[bh + t];
  const float* xbase = zx + (size_t)tok0 * DPROJ + 4096 + h * 64;
  const float* st_b = st + ((size_t)(b * 8 + c) * 64 + h) * 4096;
  for (int it = 0; it < 16; ++it) {
    int idx = it * 256 + t;
    int p = idx & 63, kg = idx >> 6;  // kg 0..63
    const float* xp = xbase + (size_t)(kg * 4) * DPROJ + p;
    sh4 o;
    o[0] = f2bf(xp[0]);
    o[1] = f2bf(xp[DPROJ]);
    o[2] = f2bf(xp[2 * DPROJ]);
    o[3] = f2bf(xp[3 * DPROJ]);
    *(sh4*)&Xs[p][kg * 4] = o;
  }
  for (int it = 0; it < 4; ++it) {
    int idx = it * 256 + t;
    int ng = idx & 15, p = idx >> 4;
    float4 v = *(const float4*)&st_b[p * 64 + ng * 4];
    sh4 o;
    o[0] = f2bf(v.x); o[1] = f2bf(v.y); o[2] = f2bf(v.z); o[3] = f2bf(v.w);
    *(sh4*)&Xs[p][256 + ng * 4] = o;
  }
  __syncthreads();

  const int fr = lane & 15, fko = (lane >> 4) * 8;
  const int wr = w * 64;
  float Al[4], eAl[4];
#pragma unroll
  for (int i = 0; i < 4; ++i) {
    Al[i] = acs[wr + i * 16 + fr];
    eAl[i] = __expf(Al[i]);
  }
  f32x4 acc[4][4];
#pragma unroll
  for (int i = 0; i < 4; ++i)
#pragma unroll
    for (int j = 0; j < 4; ++j) acc[i][j] = (f32x4){0.f, 0.f, 0.f, 0.f};

  const float* cbt_b = cbt + (size_t)(b * 8 + c) * 65536;
  const float* cct_b = cct + (size_t)(b * 8 + c) * 16384;

  // masked decay part: s in [0, wr+64)
  for (int k0 = 0; k0 < wr + 64; k0 += 32) {
    short8 bg[4];
#pragma unroll
    for (int j = 0; j < 4; ++j)
      bg[j] = *(const short8*)&Xs[j * 16 + fr][k0 + fko];
    const int bi = (k0 + 32 < 256) ? (k0 + 32) : 255;
    const float base = acs[bi];
    float vd[8];
#pragma unroll
    for (int jj = 0; jj < 8; ++jj) {
      int s = k0 + fko + jj;
      vd[jj] = __expf(base - acs[s]) * dts[s];
    }
#pragma unroll
    for (int i = 0; i < 4; ++i) {
      const int li0 = wr + i * 16;
      if (k0 > li0 + 15) continue;  // fragment fully above diagonal: zero
      const int l = li0 + fr;
      short8 af;
      if (k0 + 32 <= li0) {
        const float u = __expf(Al[i] - base);
#pragma unroll
        for (int jj = 0; jj < 8; ++jj) {
          int s = k0 + fko + jj;
          af[jj] = f2bf(cbt_b[s * 256 + l] * vd[jj] * u);
        }
      } else {
#pragma unroll
        for (int jj = 0; jj < 8; ++jj) {
          int s = k0 + fko + jj;
          float wv = 0.f;
          if (s <= l) wv = cbt_b[s * 256 + l] * __expf(Al[i] - acs[s]) * dts[s];
          af[jj] = f2bf(wv);
        }
      }
#pragma unroll
      for (int j = 0; j < 4; ++j)
        acc[i][j] = __builtin_amdgcn_mfma_f32_16x16x32_bf16(af, bg[j],
                                                            acc[i][j], 0, 0, 0);
    }
  }
  // Y_off part: k in [256, 320) -> n = k-256
#pragma unroll
  for (int k0 = 256; k0 < 320; k0 += 32) {
    short8 bg[4];
#pragma unroll
    for (int j = 0; j < 4; ++j)
      bg[j] = *(const short8*)&Xs[j * 16 + fr][k0 + fko];
#pragma unroll
    for (int i = 0; i < 4; ++i) {
      const int l = wr + i * 16 + fr;
      short8 af;
#pragma unroll
      for (int jj = 0; jj < 8; ++jj) {
        int n = k0 - 256 + fko + jj;
        af[jj] = f2bf(cct_b[n * 256 + l] * eAl[i]);
      }
#pragma unroll
      for (int j = 0; j < 4; ++j)
        acc[i][j] = __builtin_amdgcn_mfma_f32_16x16x32_bf16(af, bg[j],
                                                            acc[i][j], 0, 0, 0);
    }
  }
  // epilogue: + D*x, store
  float Dh = Dp[h];
  const int rq = (lane >> 4) * 4;
#pragma unroll
  for (int i = 0; i < 4; ++i) {
    int l0 = wr + i * 16 + rq;
#pragma unroll
    for (int j = 0; j < 4; ++j) {
      int p = j * 16 + fr;
      sh4 x4 = *(const sh4*)&Xs[p][l0];
      f32x4 a = acc[i][j];
#pragma unroll
      for (int r = 0; r < 4; ++r)
        yb[(size_t)(bh + l0 + r) * 64 + p] = a[r] + Dh * bf2f(x4[r]);
    }
  }
}

// ---------------- gate + RMSNorm -> bf16 activations (aliases zx z-slice) ----
__global__ __launch_bounds__(256) void gatenorm_kernel(
    const float* zx, const float* __restrict__ nw,
    const float* __restrict__ yb, short* ybh) {
  int tok = blockIdx.x;
  int b = tok >> 11, l = tok & 2047;
  int t = threadIdx.x;
  float g[16];
  float ss = 0.f;
#pragma unroll
  for (int i = 0; i < 16; ++i) {
    int d = i * 256 + t;
    int h = d >> 6, p = d & 63;
    float yv = yb[((size_t)(b * 64 + h) * 2048 + l) * 64 + p];
    float zv = zx[(size_t)tok * DPROJ + d];
    float gv = yv * (zv / (1.f + __expf(-zv)));
    g[i] = gv;
    ss += gv * gv;
  }
  for (int off = 32; off > 0; off >>= 1) ss += __shfl_down(ss, off);
  __shared__ float red[4];
  int wid = t >> 6, lane = t & 63;
  if (lane == 0) red[wid] = ss;
  __syncthreads();
  float tot = red[0] + red[1] + red[2] + red[3];
  float scale = rsqrtf(tot * (1.f / 4096.f) + 1e-5f);
#pragma unroll
  for (int i = 0; i < 16; ++i) {
    int d = i * 256 + t;
    ybh[(size_t)tok * 16768 + d] = f2bf(g[i] * scale * nw[d]);
  }
}

extern "C" void kernel_launch(void* const* d_in, const int* in_sizes, int n_in,
                              void* d_out, int out_size, void* d_ws,
                              size_t ws_size, hipStream_t stream) {
  const float* u = (const float*)d_in[0];
  const float* W_in = (const float*)d_in[1];
  const float* conv_w = (const float*)d_in[2];
  const float* conv_b = (const float*)d_in[3];
  const float* dt_bias = (const float*)d_in[4];
  const float* A_log = (const float*)d_in[5];
  const float* Dp = (const float*)d_in[6];
  const float* norm_w = (const float*)d_in[7];
  const float* W_out = (const float*)d_in[8];
  float* out = (float*)d_out;
  float* ws = (float*)d_ws;

  float* zx = ws + ZX_OFF;
  float* dtb = ws + DTB_OFF;
  float* acu = ws + ACU_OFF;
  float* cbtb = ws + CBT_OFF;
  float* cct = ws + CCT_OFF;
  float* st = ws + ST_OFF;
  float* yb = ws + YB_OFF;
  float* halo = ws + HALO_OFF;
  float* dtraw = ws + DTRAW_OFF;
  short* u16 = (short*)(ws + U16_OFF);
  short* win16 = (short*)(ws + WIN16_OFF);
  short* wout16 = (short*)(ws + WOUT16_OFF);
  short* ybh = (short*)zx;

  // 0. casts for in_proj
  cast_bf16_kernel<<<4096, 256, 0, stream>>>(u, u16, 1048576);
  cast_bf16_kernel<<<8384, 256, 0, stream>>>(W_in, win16, 2146304);
  // 1. in_proj (bf16 MFMA): zx = u @ W_in^T
  gemm_bf16<<<dim3(66, 32), 256, 0, stream>>>(u16, 2048, win16, 2048, zx, DPROJ,
                                              2048, DPROJ);
  // 1b. dt columns in fp32 (exp-sensitive)
  gemm_f32_nt<<<dim3(1, 32), 256, 0, stream>>>(u, W_in + 8320ul * 2048, dtraw,
                                               2048, 64);
  // 2. conv halo, in-place conv+silu
  halo_kernel<<<1584, 256, 0, stream>>>(zx, halo);
  conv_kernel<<<528, 256, 0, stream>>>(zx, halo, conv_w, conv_b);
  // 3. dt softplus + per-chunk cumsum
  dtacum_kernel<<<1024, 256, 0, stream>>>(dtraw, dt_bias, A_log, dtb, acu);
  // 4. shared C·B^T and C^T
  cbt_kernel<<<256, 256, 0, stream>>>(zx, cbtb);
  ctrans_kernel<<<1024, 256, 0, stream>>>(zx, cct);
  // 5. chunk states (MFMA) + inter-chunk scan
  states_mfma<<<1024, 256, 0, stream>>>(zx, dtb, acu, st);
  chunkscan_kernel<<<2048, 256, 0, stream>>>(acu, st);
  // 6. Y (MFMA)
  ydiag_mfma<<<1024, 256, 0, stream>>>(zx, dtb, acu, cbtb, cct, st, Dp, yb);
  // 7. W_out cast
  cast_bf16_kernel<<<4096, 256, 0, stream>>>(W_out, wout16, 1048576);
  // 8. gate + RMSNorm -> bf16
  gatenorm_kernel<<<4096, 256, 0, stream>>>(zx, norm_w, yb, ybh);
  // 9. out_proj (bf16 MFMA)
  gemm_bf16<<<dim3(16, 32), 256, 0, stream>>>(ybh, 16768, wout16, 4096, out,
                                              2048, 4096, 2048);
}

// Round 6
// 514.467 us; speedup vs baseline: 6.8950x; 1.3428x over previous
//
#include <hip/hip_runtime.h>
#include <hip/hip_bf16.h>
#include <cstdint>

// Problem constants
#define DPROJ  8384

typedef __attribute__((ext_vector_type(8))) short short8;
typedef __attribute__((ext_vector_type(4))) short sh4;
typedef __attribute__((ext_vector_type(4))) float f32x4;

// workspace offsets (float units)
#define ZX_OFF     0ul
#define DTB_OFF    34340864ul   // [b][h][l] dt (softplus'd)
#define ACU_OFF    34603008ul   // [b][h][l] within-chunk cumsum of dt*A
#define CBT_OFF    34865152ul   // bf16 cbtT [b][c][l][s]  (C·B^T transposed)
#define ST_OFF     36175872ul   // [b][c][h][p][n] states -> prev_states
#define YB_OFF     40370176ul   // [b][h][l][p] ssd output
#define HALO_OFF   57147392ul   // [b][lc][3][ch] conv halo
// aliases (disjoint lifetimes):
#define U16_OFF    40370176ul   // bf16 u  (dead before ydiag writes yb)
#define WIN16_OFF  48758784ul   // bf16 W_in (dead before halo written)
#define WOUT16_OFF 34340864ul   // bf16 W_out (written after ydiag frees dtb)

__device__ __forceinline__ short f2bf(float x) {
  union { float f; uint32_t u; } v{x};
  uint32_t r = (v.u + 0x7fff + ((v.u >> 16) & 1)) >> 16;
  return (short)r;
}
__device__ __forceinline__ float bf2f(short s) {
  union { uint32_t u; float f; } v;
  v.u = ((uint32_t)(uint16_t)s) << 16;
  return v.f;
}

// ---------------- fp32 -> bf16 cast (8 elems/thread) -------------------------
__global__ __launch_bounds__(256) void cast_bf16_kernel(
    const float* __restrict__ in, short* __restrict__ out, int n8) {
  int i = blockIdx.x * 256 + threadIdx.x;
  if (i >= n8) return;
  const float4* p = (const float4*)(in + (size_t)i * 8);
  float4 a = p[0], b = p[1];
  short8 o;
  o[0] = f2bf(a.x); o[1] = f2bf(a.y); o[2] = f2bf(a.z); o[3] = f2bf(a.w);
  o[4] = f2bf(b.x); o[5] = f2bf(b.y); o[6] = f2bf(b.z); o[7] = f2bf(b.w);
  *(short8*)(out + (size_t)i * 8) = o;
}

// ---------------- bf16 MFMA GEMM (NT): C[M][N] = A[M][K] * B[N][K]^T ---------
__device__ __forceinline__ void gload16(const void* g, const void* l) {
  __builtin_amdgcn_global_load_lds(
      (const __attribute__((address_space(1))) void*)g,
      (__attribute__((address_space(3))) void*)l, 16, 0, 0);
}

// XCD-chunked swizzle, m-fastest within chunk (gridDim.y % 8 == 0).
__global__ __launch_bounds__(256) void gemm_bf16(
    const short* __restrict__ A, int lda, const short* __restrict__ B, int ldb,
    float* __restrict__ C, int ldc, int K, int Nvalid) {
  const int orig = blockIdx.x + gridDim.x * blockIdx.y;
  const int xcd = orig & 7;
  const int cid = orig >> 3;
  const int rpx = gridDim.y >> 3;  // rows per XCD
  const int tn = cid / rpx;
  const int tm = xcd * rpx + (cid % rpx);
  __shared__ __align__(16) short As[128 * 32];
  __shared__ __align__(16) short Bs[128 * 32];
  const int t = threadIdx.x;
  const int w = t >> 6, lane = t & 63;
  const int m0 = tm * 128, n0 = tn * 128;
  const int wr = (w >> 1) * 64, wc = (w & 1) * 64;
  const int arow = t >> 2, kk = (t & 3) * 8;
  const int fr = lane & 15, fk = (lane >> 4) * 8;
  int br0 = n0 + arow;       if (br0 > Nvalid - 1) br0 = Nvalid - 1;
  int br1 = n0 + 64 + arow;  if (br1 > Nvalid - 1) br1 = Nvalid - 1;
  const short* pa0 = A + (size_t)(m0 + arow) * lda + kk;
  const short* pa1 = A + (size_t)(m0 + 64 + arow) * lda + kk;
  const short* pb0 = B + (size_t)br0 * ldb + kk;
  const short* pb1 = B + (size_t)br1 * ldb + kk;
  short* la = As + w * 512;
  short* lb = Bs + w * 512;
  f32x4 acc[4][4];
#pragma unroll
  for (int i = 0; i < 4; ++i)
#pragma unroll
    for (int j = 0; j < 4; ++j) acc[i][j] = (f32x4){0.f, 0.f, 0.f, 0.f};

  for (int k0 = 0; k0 < K; k0 += 32) {
    gload16(pa0 + k0, la);
    gload16(pa1 + k0, la + 2048);
    gload16(pb0 + k0, lb);
    gload16(pb1 + k0, lb + 2048);
    __syncthreads();
    short8 af[4], bg[4];
#pragma unroll
    for (int i = 0; i < 4; ++i) {
      af[i] = *(const short8*)&As[(wr + i * 16 + fr) * 32 + fk];
      bg[i] = *(const short8*)&Bs[(wc + i * 16 + fr) * 32 + fk];
    }
#pragma unroll
    for (int i = 0; i < 4; ++i)
#pragma unroll
      for (int j = 0; j < 4; ++j)
        acc[i][j] = __builtin_amdgcn_mfma_f32_16x16x32_bf16(af[i], bg[j],
                                                            acc[i][j], 0, 0, 0);
    __syncthreads();
  }
#pragma unroll
  for (int i = 0; i < 4; ++i) {
    const int row = m0 + wr + i * 16 + (lane >> 4) * 4;
#pragma unroll
    for (int j = 0; j < 4; ++j) {
      const int col = n0 + wc + j * 16 + fr;
      if (col < Nvalid) {
#pragma unroll
        for (int r = 0; r < 4; ++r)
          C[(size_t)(row + r) * ldc + col] = acc[i][j][r];
      }
    }
  }
}

// ---------------- conv halo save (before in-place conv) ----------------------
__global__ __launch_bounds__(256) void halo_kernel(const float* __restrict__ zx,
                                                   float* __restrict__ halo) {
  int idx = blockIdx.x * 256 + threadIdx.x;
  int ch = idx % 4224;
  int r = idx / 4224;
  int j = r % 3;
  int r2 = r / 3;
  int lc = r2 & 15, b = r2 >> 4;
  int l = lc * 128 - 3 + j;
  halo[idx] = (l < 0) ? 0.f : zx[(size_t)(b * 2048 + l) * DPROJ + 4096 + ch];
}

// ---------------- causal conv1d(4) + silu, in place on xBC slice -------------
__global__ __launch_bounds__(256) void conv_kernel(float* __restrict__ zx,
                                                   const float* __restrict__ halo,
                                                   const float* __restrict__ cw,
                                                   const float* __restrict__ cb) {
  int idx = blockIdx.x * 256 + threadIdx.x;
  int ch = idx % 4224;
  int r = idx / 4224;
  int lc = r & 15, b = r >> 4;
  float w0 = cw[ch * 4 + 0], w1 = cw[ch * 4 + 1], w2 = cw[ch * 4 + 2],
        w3 = cw[ch * 4 + 3];
  float bias = cb[ch];
  const float* hp = halo + (size_t)r * 3 * 4224 + ch;
  float x3 = hp[0], x2 = hp[4224], x1 = hp[2 * 4224];
  size_t base = (size_t)(b * 2048 + lc * 128) * DPROJ + 4096 + ch;
  for (int i = 0; i < 128; ++i) {
    float x0 = zx[base];
    float v = bias + w0 * x3 + w1 * x2 + w2 * x1 + w3 * x0;
    v = v / (1.f + __expf(-v));
    zx[base] = v;
    x3 = x2; x2 = x1; x1 = x0;
    base += DPROJ;
  }
}

// ---------------- dt softplus + per-chunk cumsum of dt*A ---------------------
// reads the dt columns of zx (from the fused bf16 in_proj GEMM)
__global__ __launch_bounds__(256) void dtacum_kernel(
    const float* __restrict__ zx, const float* __restrict__ dt_bias,
    const float* __restrict__ A_log, float* __restrict__ dtb,
    float* __restrict__ acu) {
  int bid = blockIdx.x;
  int c = bid & 7, h = (bid >> 3) & 63, b = bid >> 9;
  int s = threadIdx.x;
  int tok = b * 2048 + c * 256 + s;
  float raw = zx[(size_t)tok * DPROJ + 8320 + h] + dt_bias[h];
  float dtv = (raw > 20.f) ? raw : log1pf(expf(raw));
  float A = -expf(A_log[h]);
  __shared__ float sc[256];
  sc[s] = dtv * A;
  __syncthreads();
  for (int off = 1; off < 256; off <<= 1) {
    float v = (s >= off) ? sc[s - off] : 0.f;
    __syncthreads();
    sc[s] += v;
    __syncthreads();
  }
  int o = (b * 64 + h) * 2048 + c * 256 + s;
  dtb[o] = dtv;
  acu[o] = sc[s];
}

// ---------------- CB^T per (b,c), TRANSPOSED bf16: cbtT[l][s] ----------------
__global__ __launch_bounds__(256) void cbt_kernel(const float* __restrict__ zx,
                                                  short* __restrict__ cbtT) {
  __shared__ float cl[256][33];
  __shared__ float blds[16][32];
  int bid = blockIdx.x;
  int sb = bid & 15, c = (bid >> 4) & 7, b = bid >> 7;
  int t = threadIdx.x;  // = l
  int tok0 = b * 2048 + c * 256;
  float acc[16];
#pragma unroll
  for (int i = 0; i < 16; ++i) acc[i] = 0.f;
  for (int nh = 0; nh < 2; ++nh) {
    __syncthreads();
    for (int it = 0; it < 32; ++it) {
      int e = it * 256 + t;
      int row = e >> 5, n = e & 31;
      cl[row][n] = zx[(size_t)(tok0 + row) * DPROJ + 8256 + nh * 32 + n];
    }
    for (int it = 0; it < 2; ++it) {
      int e = it * 256 + t;
      int row = e >> 5, n = e & 31;
      blds[row][n] =
          zx[(size_t)(tok0 + sb * 16 + row) * DPROJ + 8192 + nh * 32 + n];
    }
    __syncthreads();
    for (int n = 0; n < 32; ++n) {
      float cv = cl[t][n];
#pragma unroll
      for (int s2 = 0; s2 < 16; ++s2) acc[s2] += cv * blds[s2][n];
    }
  }
  short* outp = cbtT + ((size_t)(b * 8 + c) * 256 + t) * 256 + sb * 16;
#pragma unroll
  for (int s2 = 0; s2 < 16; ++s2) outp[s2] = f2bf(acc[s2]);
}

// ---------------- states (MFMA): st[p][n] = sum_s x[s,p] B[s,n] w[s] ---------
__global__ __launch_bounds__(256) void states_mfma(
    const float* __restrict__ zx, const float* __restrict__ dtb,
    const float* __restrict__ acu, float* __restrict__ st) {
  __shared__ __align__(16) short As2[64][136];  // X^T [p][k]
  __shared__ __align__(16) short Bs2[64][136];  // (B·w)^T [n][k]
  __shared__ float wl[256];
  int bid = blockIdx.x;  // (b*8+c)*64 + h
  int h = bid & 63, c = (bid >> 6) & 7, b = bid >> 9;
  int t = threadIdx.x;
  int w = t >> 6, lane = t & 63;
  int tok0 = b * 2048 + c * 256;
  int bh = (b * 64 + h) * 2048 + c * 256;
  {
    float aend = acu[bh + 255];
    wl[t] = __expf(aend - acu[bh + t]) * dtb[bh + t];
  }
  __syncthreads();
  const float* xbase = zx + (size_t)tok0 * DPROJ + 4096 + h * 64;
  const float* bbase = zx + (size_t)tok0 * DPROJ + 8192;
  const int fr = lane & 15, fko = (lane >> 4) * 8;
  const int wi = (w >> 1) * 32, wj = (w & 1) * 32;
  f32x4 acc[2][2];
#pragma unroll
  for (int i = 0; i < 2; ++i)
#pragma unroll
    for (int j = 0; j < 2; ++j) acc[i][j] = (f32x4){0.f, 0.f, 0.f, 0.f};

  for (int ph = 0; ph < 2; ++ph) {
    const int kb = ph * 128;
    if (ph) __syncthreads();
    for (int it = 0; it < 8; ++it) {
      int idx = it * 256 + t;
      int p = idx & 63, kg = idx >> 6;  // kg 0..31
      int k = kb + kg * 4;
      const float* xp = xbase + (size_t)k * DPROJ + p;
      const float* bp = bbase + (size_t)k * DPROJ + p;
      sh4 oa, ob;
#pragma unroll
      for (int r = 0; r < 4; ++r) {
        oa[r] = f2bf(xp[(size_t)r * DPROJ]);
        ob[r] = f2bf(bp[(size_t)r * DPROJ] * wl[k + r]);
      }
      *(sh4*)&As2[p][kg * 4] = oa;
      *(sh4*)&Bs2[p][kg * 4] = ob;
    }
    __syncthreads();
#pragma unroll
    for (int kk0 = 0; kk0 < 128; kk0 += 32) {
      short8 af[2], bg[2];
#pragma unroll
      for (int i = 0; i < 2; ++i) {
        af[i] = *(const short8*)&As2[wi + i * 16 + fr][kk0 + fko];
        bg[i] = *(const short8*)&Bs2[wj + i * 16 + fr][kk0 + fko];
      }
#pragma unroll
      for (int i = 0; i < 2; ++i)
#pragma unroll
        for (int j = 0; j < 2; ++j)
          acc[i][j] = __builtin_amdgcn_mfma_f32_16x16x32_bf16(af[i], bg[j],
                                                              acc[i][j], 0, 0, 0);
    }
  }
  float* out = st + ((size_t)(b * 8 + c) * 64 + h) * 4096;
  const int rq = (lane >> 4) * 4;
#pragma unroll
  for (int i = 0; i < 2; ++i) {
    int p0 = wi + i * 16 + rq;
#pragma unroll
    for (int j = 0; j < 2; ++j) {
      int n = wj + j * 16 + fr;
#pragma unroll
      for (int r = 0; r < 4; ++r)
        out[(size_t)(p0 + r) * 64 + n] = acc[i][j][r];
    }
  }
}

// ---------------- inter-chunk scan (in place states -> prev_states) ---------
__global__ __launch_bounds__(256) void chunkscan_kernel(
    const float* __restrict__ acu, float* __restrict__ st) {
  int bid = blockIdx.x;
  int pc = bid & 15, h = (bid >> 4) & 63, b = bid >> 10;
  int pn = pc * 256 + threadIdx.x;
  int abase = (b * 64 + h) * 2048;
  float run = 0.f;
  for (int c = 0; c < 8; ++c) {
    size_t idx = ((size_t)(b * 8 + c) * 64 + h) * 4096 + pn;
    float s = st[idx];
    st[idx] = run;
    float ach = acu[abase + c * 256 + 255];
    run = run * __expf(ach) + s;
  }
}

// ---------------- Y (MFMA): M=256 l, N=64 p, K=320 (256 s + 64 n) ------------
// A-fragments: cbtT[l][s] bf16 vector loads; C read directly from zx.
// Rank-1 rebased decay below the diagonal.
__global__ __launch_bounds__(256) void ydiag_mfma(
    const float* __restrict__ zx, const float* __restrict__ dtb,
    const float* __restrict__ acu, const short* __restrict__ cbtT,
    const float* __restrict__ st, const float* __restrict__ Dp,
    float* __restrict__ yb) {
  __shared__ __align__(16) short Xs[64][328];  // [p][k]: k<256 x, k>=256 prev
  __shared__ float acs[256];
  __shared__ float dts[256];
  int bid = blockIdx.x;  // (b*8+c)*64 + h
  int h = bid & 63, c = (bid >> 6) & 7, b = bid >> 9;
  int t = threadIdx.x;
  int w = t >> 6, lane = t & 63;
  int tok0 = b * 2048 + c * 256;
  int bh = (b * 64 + h) * 2048 + c * 256;
  acs[t] = acu[bh + t];
  dts[t] = dtb[bh + t];
  const float* xbase = zx + (size_t)tok0 * DPROJ + 4096 + h * 64;
  const float* st_b = st + ((size_t)(b * 8 + c) * 64 + h) * 4096;
  for (int it = 0; it < 16; ++it) {
    int idx = it * 256 + t;
    int p = idx & 63, kg = idx >> 6;  // kg 0..63
    const float* xp = xbase + (size_t)(kg * 4) * DPROJ + p;
    sh4 o;
    o[0] = f2bf(xp[0]);
    o[1] = f2bf(xp[DPROJ]);
    o[2] = f2bf(xp[2 * DPROJ]);
    o[3] = f2bf(xp[3 * DPROJ]);
    *(sh4*)&Xs[p][kg * 4] = o;
  }
  for (int it = 0; it < 4; ++it) {
    int idx = it * 256 + t;
    int ng = idx & 15, p = idx >> 4;
    float4 v = *(const float4*)&st_b[p * 64 + ng * 4];
    sh4 o;
    o[0] = f2bf(v.x); o[1] = f2bf(v.y); o[2] = f2bf(v.z); o[3] = f2bf(v.w);
    *(sh4*)&Xs[p][256 + ng * 4] = o;
  }
  __syncthreads();

  const int fr = lane & 15, fko = (lane >> 4) * 8;
  const int wr = w * 64;
  float Al[4], eAl[4];
#pragma unroll
  for (int i = 0; i < 4; ++i) {
    Al[i] = acs[wr + i * 16 + fr];
    eAl[i] = __expf(Al[i]);
  }
  f32x4 acc[4][4];
#pragma unroll
  for (int i = 0; i < 4; ++i)
#pragma unroll
    for (int j = 0; j < 4; ++j) acc[i][j] = (f32x4){0.f, 0.f, 0.f, 0.f};

  const short* cbt_b = cbtT + (size_t)(b * 8 + c) * 65536;

  // masked decay part: s in [0, wr+64)
  for (int k0 = 0; k0 < wr + 64; k0 += 32) {
    short8 bg[4];
#pragma unroll
    for (int j = 0; j < 4; ++j)
      bg[j] = *(const short8*)&Xs[j * 16 + fr][k0 + fko];
    const int bi = (k0 + 32 < 256) ? (k0 + 32) : 255;
    const float base = acs[bi];
    float vd[8];
#pragma unroll
    for (int jj = 0; jj < 8; ++jj) {
      int s = k0 + fko + jj;
      vd[jj] = __expf(base - acs[s]) * dts[s];
    }
#pragma unroll
    for (int i = 0; i < 4; ++i) {
      const int li0 = wr + i * 16;
      if (k0 > li0 + 15) continue;  // fragment fully above diagonal: zero
      const int l = li0 + fr;
      const short8 cb = *(const short8*)&cbt_b[(size_t)l * 256 + k0 + fko];
      short8 af;
      if (k0 + 32 <= li0) {
        const float u = __expf(Al[i] - base);
#pragma unroll
        for (int jj = 0; jj < 8; ++jj)
          af[jj] = f2bf(bf2f(cb[jj]) * (vd[jj] * u));
      } else {
#pragma unroll
        for (int jj = 0; jj < 8; ++jj) {
          int s = k0 + fko + jj;
          float wv = 0.f;
          if (s <= l) wv = bf2f(cb[jj]) * __expf(Al[i] - acs[s]) * dts[s];
          af[jj] = f2bf(wv);
        }
      }
#pragma unroll
      for (int j = 0; j < 4; ++j)
        acc[i][j] = __builtin_amdgcn_mfma_f32_16x16x32_bf16(af, bg[j],
                                                            acc[i][j], 0, 0, 0);
    }
  }
  // Y_off part: k in [256, 320) -> n = k-256; C read straight from zx
#pragma unroll
  for (int k0 = 256; k0 < 320; k0 += 32) {
    short8 bg[4];
#pragma unroll
    for (int j = 0; j < 4; ++j)
      bg[j] = *(const short8*)&Xs[j * 16 + fr][k0 + fko];
#pragma unroll
    for (int i = 0; i < 4; ++i) {
      const int l = wr + i * 16 + fr;
      const float* cr =
          zx + (size_t)(tok0 + l) * DPROJ + 8256 + (k0 - 256) + fko;
      float4 c0 = *(const float4*)cr;
      float4 c1 = *(const float4*)(cr + 4);
      short8 af;
      af[0] = f2bf(c0.x * eAl[i]); af[1] = f2bf(c0.y * eAl[i]);
      af[2] = f2bf(c0.z * eAl[i]); af[3] = f2bf(c0.w * eAl[i]);
      af[4] = f2bf(c1.x * eAl[i]); af[5] = f2bf(c1.y * eAl[i]);
      af[6] = f2bf(c1.z * eAl[i]); af[7] = f2bf(c1.w * eAl[i]);
#pragma unroll
      for (int j = 0; j < 4; ++j)
        acc[i][j] = __builtin_amdgcn_mfma_f32_16x16x32_bf16(af, bg[j],
                                                            acc[i][j], 0, 0, 0);
    }
  }
  // epilogue: + D*x, store
  float Dh = Dp[h];
  const int rq = (lane >> 4) * 4;
#pragma unroll
  for (int i = 0; i < 4; ++i) {
    int l0 = wr + i * 16 + rq;
#pragma unroll
    for (int j = 0; j < 4; ++j) {
      int p = j * 16 + fr;
      sh4 x4 = *(const sh4*)&Xs[p][l0];
      f32x4 a = acc[i][j];
#pragma unroll
      for (int r = 0; r < 4; ++r)
        yb[(size_t)(bh + l0 + r) * 64 + p] = a[r] + Dh * bf2f(x4[r]);
    }
  }
}

// ---------------- gate + RMSNorm -> bf16 activations (aliases zx z-slice) ----
__global__ __launch_bounds__(256) void gatenorm_kernel(
    const float* zx, const float* __restrict__ nw,
    const float* __restrict__ yb, short* ybh) {
  int tok = blockIdx.x;
  int b = tok >> 11, l = tok & 2047;
  int t = threadIdx.x;
  float g[16];
  float ss = 0.f;
#pragma unroll
  for (int i = 0; i < 16; ++i) {
    int d = i * 256 + t;
    int h = d >> 6, p = d & 63;
    float yv = yb[((size_t)(b * 64 + h) * 2048 + l) * 64 + p];
    float zv = zx[(size_t)tok * DPROJ + d];
    float gv = yv * (zv / (1.f + __expf(-zv)));
    g[i] = gv;
    ss += gv * gv;
  }
  for (int off = 32; off > 0; off >>= 1) ss += __shfl_down(ss, off);
  __shared__ float red[4];
  int wid = t >> 6, lane = t & 63;
  if (lane == 0) red[wid] = ss;
  __syncthreads();
  float tot = red[0] + red[1] + red[2] + red[3];
  float scale = rsqrtf(tot * (1.f / 4096.f) + 1e-5f);
#pragma unroll
  for (int i = 0; i < 16; ++i) {
    int d = i * 256 + t;
    ybh[(size_t)tok * 16768 + d] = f2bf(g[i] * scale * nw[d]);
  }
}

extern "C" void kernel_launch(void* const* d_in, const int* in_sizes, int n_in,
                              void* d_out, int out_size, void* d_ws,
                              size_t ws_size, hipStream_t stream) {
  const float* u = (const float*)d_in[0];
  const float* W_in = (const float*)d_in[1];
  const float* conv_w = (const float*)d_in[2];
  const float* conv_b = (const float*)d_in[3];
  const float* dt_bias = (const float*)d_in[4];
  const float* A_log = (const float*)d_in[5];
  const float* Dp = (const float*)d_in[6];
  const float* norm_w = (const float*)d_in[7];
  const float* W_out = (const float*)d_in[8];
  float* out = (float*)d_out;
  float* ws = (float*)d_ws;

  float* zx = ws + ZX_OFF;
  float* dtb = ws + DTB_OFF;
  float* acu = ws + ACU_OFF;
  short* cbtT = (short*)(ws + CBT_OFF);
  float* st = ws + ST_OFF;
  float* yb = ws + YB_OFF;
  float* halo = ws + HALO_OFF;
  short* u16 = (short*)(ws + U16_OFF);
  short* win16 = (short*)(ws + WIN16_OFF);
  short* wout16 = (short*)(ws + WOUT16_OFF);
  short* ybh = (short*)zx;

  // 0. casts for in_proj
  cast_bf16_kernel<<<4096, 256, 0, stream>>>(u, u16, 1048576);
  cast_bf16_kernel<<<8384, 256, 0, stream>>>(W_in, win16, 2146304);
  // 1. in_proj (bf16 MFMA): zx = u @ W_in^T (dt columns fused)
  gemm_bf16<<<dim3(66, 32), 256, 0, stream>>>(u16, 2048, win16, 2048, zx, DPROJ,
                                              2048, DPROJ);
  // 2. conv halo, in-place conv+silu
  halo_kernel<<<1584, 256, 0, stream>>>(zx, halo);
  conv_kernel<<<528, 256, 0, stream>>>(zx, halo, conv_w, conv_b);
  // 3. dt softplus + per-chunk cumsum (reads zx dt slice)
  dtacum_kernel<<<1024, 256, 0, stream>>>(zx, dt_bias, A_log, dtb, acu);
  // 4. shared C·B^T (transposed bf16)
  cbt_kernel<<<256, 256, 0, stream>>>(zx, cbtT);
  // 5. chunk states (MFMA) + inter-chunk scan
  states_mfma<<<1024, 256, 0, stream>>>(zx, dtb, acu, st);
  chunkscan_kernel<<<2048, 256, 0, stream>>>(acu, st);
  // 6. Y (MFMA)
  ydiag_mfma<<<1024, 256, 0, stream>>>(zx, dtb, acu, cbtT, st, Dp, yb);
  // 7. W_out cast
  cast_bf16_kernel<<<4096, 256, 0, stream>>>(W_out, wout16, 1048576);
  // 8. gate + RMSNorm -> bf16
  gatenorm_kernel<<<4096, 256, 0, stream>>>(zx, norm_w, yb, ybh);
  // 9. out_proj (bf16 MFMA)
  gemm_bf16<<<dim3(16, 32), 256, 0, stream>>>(ybh, 16768, wout16, 4096, out,
                                              2048, 4096, 2048);
}